// Round 1
// baseline (321.489 us; speedup 1.0000x reference)
//
#include <hip/hip_runtime.h>
#include <math.h>

#define Bb 32
#define Nn 400
#define Dd 128
#define Hh 8
#define QKd 16
#define FFd 512
#define Ee 8
#define Tt (Bb*Nn)   // 12800

// ---------------- K1: QKV projection ----------------
// grid (400, 3), block 256. Computes q/k/v in [B,H,N,QK] layout.
__global__ __launch_bounds__(256) void qkv_kernel(const float* __restrict__ x,
    const float* __restrict__ Wq, const float* __restrict__ Wk, const float* __restrict__ Wv,
    float* __restrict__ q, float* __restrict__ k, float* __restrict__ v)
{
  __shared__ float xs[32][128];
  const int tid = threadIdx.x;
  const int t0 = blockIdx.x * 32;
  const int sel = blockIdx.y;
  const float* __restrict__ W = (sel == 0) ? Wq : (sel == 1) ? Wk : Wv;
  float* __restrict__ O = (sel == 0) ? q : (sel == 1) ? k : v;

  #pragma unroll
  for (int it = 0; it < 16; ++it) {
    int lin = it * 256 + tid;
    int r = lin >> 7, c = lin & 127;
    xs[r][c] = x[(t0 + r) * Dd + c];
  }
  __syncthreads();

  const int c = tid & 127;
  const int rb = (tid >> 7) * 16;
  float acc[16];
  #pragma unroll
  for (int r = 0; r < 16; ++r) acc[r] = 0.f;

  for (int d4 = 0; d4 < 32; ++d4) {
    float w0 = W[(d4*4+0)*128 + c];
    float w1 = W[(d4*4+1)*128 + c];
    float w2 = W[(d4*4+2)*128 + c];
    float w3 = W[(d4*4+3)*128 + c];
    #pragma unroll
    for (int r = 0; r < 16; ++r) {
      float4 xv = *(const float4*)&xs[rb + r][d4*4];
      acc[r] += xv.x*w0 + xv.y*w1 + xv.z*w2 + xv.w*w3;
    }
  }
  const int h = c >> 4, j = c & 15;
  #pragma unroll
  for (int r = 0; r < 16; ++r) {
    int t = t0 + rb + r;
    int b = t / Nn, n = t % Nn;
    O[((b*Hh + h)*Nn + n)*QKd + j] = acc[r];
  }
}

// ---------------- K2: attention (online softmax) ----------------
// grid (256, 2): blockIdx.x = b*H+h, blockIdx.y = which half of the 400 rows.
__global__ __launch_bounds__(256) void attn_kernel(const float* __restrict__ q,
    const float* __restrict__ k, const float* __restrict__ v, float* __restrict__ attn)
{
  __shared__ float ks[Nn * QKd];
  __shared__ float vs[Nn * QKd];
  const int tid = threadIdx.x;
  const int bh = blockIdx.x;
  const int base = bh * Nn * QKd;   // 6400

  #pragma unroll
  for (int it = 0; it < 25; ++it) {
    int lin = it * 256 + tid;
    ks[lin] = k[base + lin];
    vs[lin] = v[base + lin];
  }
  __syncthreads();

  if (tid >= 200) return;
  const int i = blockIdx.y * 200 + tid;

  float qr[16];
  const float4* qp = (const float4*)&q[base + i * QKd];
  #pragma unroll
  for (int jj = 0; jj < 4; ++jj) {
    float4 qv = qp[jj];
    qr[jj*4+0] = qv.x; qr[jj*4+1] = qv.y; qr[jj*4+2] = qv.z; qr[jj*4+3] = qv.w;
  }

  float m = -INFINITY, l = 0.f;
  float acc[16];
  #pragma unroll
  for (int jj = 0; jj < 16; ++jj) acc[jj] = 0.f;

  for (int mm = 0; mm < Nn; ++mm) {
    const float* kr = &ks[mm * QKd];
    float s = 0.f;
    #pragma unroll
    for (int jj = 0; jj < 16; ++jj) s += qr[jj] * kr[jj];
    s *= 0.25f;                       // 1/sqrt(16)
    float mn = fmaxf(m, s);
    float corr = __expf(m - mn);      // first iter: exp(-inf)=0
    float p = __expf(s - mn);
    l = l * corr + p;
    const float* vr = &vs[mm * QKd];
    #pragma unroll
    for (int jj = 0; jj < 16; ++jj) acc[jj] = acc[jj] * corr + p * vr[jj];
    m = mn;
  }
  const int b = bh >> 3, h = bh & 7;
  const int t = b * Nn + i;
  float inv = 1.f / l;
  #pragma unroll
  for (int jj = 0; jj < 16; ++jj) attn[t * Dd + h * QKd + jj] = acc[jj] * inv;
}

// ---------------- K3: output proj + residual + LN1 ----------------
// grid 6400, block 256 (2 tokens/block).
__global__ __launch_bounds__(256) void proj_ln1_kernel(const float* __restrict__ x,
    const float* __restrict__ attn, const float* __restrict__ Wo, const float* __restrict__ bo,
    const float* __restrict__ g, const float* __restrict__ bb, float* __restrict__ out1)
{
  __shared__ float arow[2][128];
  __shared__ float red[8];
  const int tid = threadIdx.x;
  const int half = tid >> 7;
  const int j = tid & 127;
  const int t = blockIdx.x * 2 + half;
  arow[half][j] = attn[t * Dd + j];
  __syncthreads();

  float acc = bo[j];
  for (int d4 = 0; d4 < 32; ++d4) {
    float4 av = *(const float4*)&arow[half][d4*4];
    acc += av.x * Wo[(d4*4+0)*Dd + j] + av.y * Wo[(d4*4+1)*Dd + j]
         + av.z * Wo[(d4*4+2)*Dd + j] + av.w * Wo[(d4*4+3)*Dd + j];
  }
  float r = x[t * Dd + j] + acc;

  float s = r;
  #pragma unroll
  for (int off = 32; off > 0; off >>= 1) s += __shfl_xor(s, off, 64);
  const int wid = tid >> 6;
  if ((tid & 63) == 0) red[wid] = s;
  __syncthreads();
  float mean = (red[half*2] + red[half*2+1]) * (1.f/128.f);
  float dv = r - mean;
  float s2 = dv * dv;
  #pragma unroll
  for (int off = 32; off > 0; off >>= 1) s2 += __shfl_xor(s2, off, 64);
  if ((tid & 63) == 0) red[4 + wid] = s2;
  __syncthreads();
  float var = (red[4 + half*2] + red[4 + half*2+1]) * (1.f/128.f);
  out1[t * Dd + j] = dv * rsqrtf(var + 1e-5f) * g[j] + bb[j];
}

// ---------------- K4: gating + top-2 + compaction ----------------
// grid 50, block 256 (1 token/thread).
__global__ __launch_bounds__(256) void gate_kernel(const float* __restrict__ out1,
    const float* __restrict__ w_gate,
    int* __restrict__ cnt, float* __restrict__ imp, float* __restrict__ loadv,
    int* __restrict__ etok, float* __restrict__ egate)
{
  __shared__ float wg[128 * 8];
  __shared__ float s_imp[8], s_load[8];
  __shared__ int s_cnt[8], s_base[8];
  const int tid = threadIdx.x;
  #pragma unroll
  for (int it = 0; it < 4; ++it) wg[it * 256 + tid] = w_gate[it * 256 + tid];
  if (tid < 8) { s_imp[tid] = 0.f; s_load[tid] = 0.f; s_cnt[tid] = 0; }
  __syncthreads();

  const int t = blockIdx.x * 256 + tid;
  float lg[8];
  #pragma unroll
  for (int e = 0; e < 8; ++e) lg[e] = 0.f;
  for (int d4 = 0; d4 < 32; ++d4) {
    float4 xv = *(const float4*)&out1[t * Dd + d4*4];
    #pragma unroll
    for (int e = 0; e < 8; ++e)
      lg[e] += xv.x * wg[(d4*4+0)*8+e] + xv.y * wg[(d4*4+1)*8+e]
             + xv.z * wg[(d4*4+2)*8+e] + xv.w * wg[(d4*4+3)*8+e];
  }
  // top-2 (strict >, so ties pick lowest index like lax.top_k)
  int i0 = 0; float v0 = lg[0];
  #pragma unroll
  for (int e = 1; e < 8; ++e) if (lg[e] > v0) { v0 = lg[e]; i0 = e; }
  int i1 = -1; float v1 = -INFINITY;
  #pragma unroll
  for (int e = 0; e < 8; ++e) if (e != i0 && lg[e] > v1) { v1 = lg[e]; i1 = e; }
  float g0 = 1.f / (1.f + __expf(v1 - v0));
  float g1 = 1.f - g0;

  atomicAdd(&s_imp[i0], g0);  atomicAdd(&s_imp[i1], g1);
  atomicAdd(&s_load[i0], 1.f); atomicAdd(&s_load[i1], 1.f);
  int p0 = atomicAdd(&s_cnt[i0], 1);
  int p1 = atomicAdd(&s_cnt[i1], 1);
  __syncthreads();
  if (tid < 8) {
    s_base[tid] = atomicAdd(&cnt[tid], s_cnt[tid]);
    atomicAdd(&imp[tid], s_imp[tid]);
    atomicAdd(&loadv[tid], s_load[tid]);
  }
  __syncthreads();
  int o0 = i0 * Tt + s_base[i0] + p0;
  etok[o0] = t; egate[o0] = g0;
  int o1 = i1 * Tt + s_base[i1] + p1;
  etok[o1] = t; egate[o1] = g1;
}

// ---------------- K5: moe aux loss ----------------
__global__ void loss_kernel(const float* __restrict__ imp, const float* __restrict__ loadv,
                            float* __restrict__ out_loss)
{
  if (threadIdx.x == 0) {
    float m1 = 0.f;
    for (int e = 0; e < 8; ++e) m1 += imp[e];
    m1 *= 0.125f;
    float v1 = 0.f;
    for (int e = 0; e < 8; ++e) { float d = imp[e] - m1; v1 += d * d; }
    v1 *= 0.125f;
    float c1 = v1 / (m1 * m1 + 1e-10f);
    float m2 = 0.f;
    for (int e = 0; e < 8; ++e) m2 += loadv[e];
    m2 *= 0.125f;
    float v2 = 0.f;
    for (int e = 0; e < 8; ++e) { float d = loadv[e] - m2; v2 += d * d; }
    v2 *= 0.125f;
    float c2 = v2 / (m2 * m2 + 1e-10f);
    out_loss[0] = (c1 + c2) * 0.01f;
  }
}

// ---------------- K6: grouped sparse MoE FFN ----------------
// grid (200, 8): blockIdx.y = expert, blockIdx.x = 64-token tile of its list.
__global__ __launch_bounds__(256) void moe_kernel(const float* __restrict__ out1,
    const float* __restrict__ W1, const float* __restrict__ b1,
    const float* __restrict__ W2, const float* __restrict__ b2,
    const int* __restrict__ cnt, const int* __restrict__ etok, const float* __restrict__ egate,
    float* __restrict__ moe)
{
  __shared__ float xs[64][128];   // 32KB
  __shared__ float hs[64][128];   // 32KB (FF processed in 4 chunks of 128)
  const int e = blockIdx.y;
  const int count = cnt[e];
  const int t0 = blockIdx.x * 64;
  if (t0 >= count) return;
  const int nt = min(64, count - t0);
  const int tid = threadIdx.x;
  const int* __restrict__ el = etok + e * Tt + t0;
  const float* __restrict__ gl = egate + e * Tt + t0;

  #pragma unroll
  for (int it = 0; it < 32; ++it) {
    int lin = it * 256 + tid;
    int r = lin >> 7, c = lin & 127;
    int rr = (r < nt) ? r : 0;
    xs[r][c] = out1[el[rr] * Dd + c];
  }
  __syncthreads();

  const int c2 = tid & 63;
  const int rb = (tid >> 6) * 16;
  float y[16][2];
  #pragma unroll
  for (int r = 0; r < 16; ++r) { y[r][0] = b2[e*Dd + c2]; y[r][1] = b2[e*Dd + 64 + c2]; }

  for (int ch = 0; ch < 4; ++ch) {
    const int f0 = ch * 128 + c2;
    float hacc[16][2];
    #pragma unroll
    for (int r = 0; r < 16; ++r) { hacc[r][0] = b1[e*FFd + f0]; hacc[r][1] = b1[e*FFd + f0 + 64]; }

    for (int d4 = 0; d4 < 32; ++d4) {
      float wa0 = W1[(e*Dd + d4*4+0)*FFd + f0];
      float wa1 = W1[(e*Dd + d4*4+1)*FFd + f0];
      float wa2 = W1[(e*Dd + d4*4+2)*FFd + f0];
      float wa3 = W1[(e*Dd + d4*4+3)*FFd + f0];
      float wb0 = W1[(e*Dd + d4*4+0)*FFd + f0 + 64];
      float wb1 = W1[(e*Dd + d4*4+1)*FFd + f0 + 64];
      float wb2 = W1[(e*Dd + d4*4+2)*FFd + f0 + 64];
      float wb3 = W1[(e*Dd + d4*4+3)*FFd + f0 + 64];
      #pragma unroll
      for (int r = 0; r < 16; ++r) {
        float4 xv = *(const float4*)&xs[rb + r][d4*4];
        hacc[r][0] += xv.x*wa0 + xv.y*wa1 + xv.z*wa2 + xv.w*wa3;
        hacc[r][1] += xv.x*wb0 + xv.y*wb1 + xv.z*wb2 + xv.w*wb3;
      }
    }
    __syncthreads();   // previous chunk's hs reads are done
    #pragma unroll
    for (int r = 0; r < 16; ++r) {
      hs[rb + r][c2]      = fmaxf(hacc[r][0], 0.f);
      hs[rb + r][c2 + 64] = fmaxf(hacc[r][1], 0.f);
    }
    __syncthreads();
    for (int f4 = 0; f4 < 32; ++f4) {
      float wa0 = W2[(e*FFd + ch*128 + f4*4+0)*Dd + c2];
      float wa1 = W2[(e*FFd + ch*128 + f4*4+1)*Dd + c2];
      float wa2 = W2[(e*FFd + ch*128 + f4*4+2)*Dd + c2];
      float wa3 = W2[(e*FFd + ch*128 + f4*4+3)*Dd + c2];
      float wb0 = W2[(e*FFd + ch*128 + f4*4+0)*Dd + c2 + 64];
      float wb1 = W2[(e*FFd + ch*128 + f4*4+1)*Dd + c2 + 64];
      float wb2 = W2[(e*FFd + ch*128 + f4*4+2)*Dd + c2 + 64];
      float wb3 = W2[(e*FFd + ch*128 + f4*4+3)*Dd + c2 + 64];
      #pragma unroll
      for (int r = 0; r < 16; ++r) {
        float4 hv = *(const float4*)&hs[rb + r][f4*4];
        y[r][0] += hv.x*wa0 + hv.y*wa1 + hv.z*wa2 + hv.w*wa3;
        y[r][1] += hv.x*wb0 + hv.y*wb1 + hv.z*wb2 + hv.w*wb3;
      }
    }
  }
  #pragma unroll
  for (int r = 0; r < 16; ++r) {
    if (rb + r < nt) {
      int tt = el[rb + r];
      float gg = gl[rb + r];
      atomicAdd(&moe[tt*Dd + c2],      gg * y[r][0]);
      atomicAdd(&moe[tt*Dd + c2 + 64], gg * y[r][1]);
    }
  }
}

// ---------------- K7: residual + LN2 -> d_out ----------------
__global__ __launch_bounds__(256) void ln2_kernel(const float* __restrict__ out1,
    const float* __restrict__ moe, const float* __restrict__ g, const float* __restrict__ bb,
    float* __restrict__ out)
{
  __shared__ float red[8];
  const int tid = threadIdx.x;
  const int half = tid >> 7;
  const int j = tid & 127;
  const int t = blockIdx.x * 2 + half;
  float r = out1[t * Dd + j] + moe[t * Dd + j];

  float s = r;
  #pragma unroll
  for (int off = 32; off > 0; off >>= 1) s += __shfl_xor(s, off, 64);
  const int wid = tid >> 6;
  if ((tid & 63) == 0) red[wid] = s;
  __syncthreads();
  float mean = (red[half*2] + red[half*2+1]) * (1.f/128.f);
  float dv = r - mean;
  float s2 = dv * dv;
  #pragma unroll
  for (int off = 32; off > 0; off >>= 1) s2 += __shfl_xor(s2, off, 64);
  if ((tid & 63) == 0) red[4 + wid] = s2;
  __syncthreads();
  float var = (red[4 + half*2] + red[4 + half*2+1]) * (1.f/128.f);
  out[t * Dd + j] = dv * rsqrtf(var + 1e-5f) * g[j] + bb[j];
}

extern "C" void kernel_launch(void* const* d_in, const int* in_sizes, int n_in,
                              void* d_out, int out_size, void* d_ws, size_t ws_size,
                              hipStream_t stream)
{
  (void)in_sizes; (void)n_in; (void)out_size; (void)ws_size;
  const float* x      = (const float*)d_in[0];
  const float* Wq     = (const float*)d_in[1];
  const float* Wk     = (const float*)d_in[2];
  const float* Wv     = (const float*)d_in[3];
  const float* Wo     = (const float*)d_in[4];
  const float* bo     = (const float*)d_in[5];
  const float* ln1_g  = (const float*)d_in[6];
  const float* ln1_b  = (const float*)d_in[7];
  const float* w_gate = (const float*)d_in[8];
  const float* W1     = (const float*)d_in[9];
  const float* b1     = (const float*)d_in[10];
  const float* W2     = (const float*)d_in[11];
  const float* b2     = (const float*)d_in[12];
  const float* ln2_g  = (const float*)d_in[13];
  const float* ln2_b  = (const float*)d_in[14];

  float* ws   = (float*)d_ws;
  float* q    = ws + 0;                  // 1,638,400 floats; reused as moe accumulator
  float* kk   = ws + 1638400;            // reused for gating/compaction after attention
  float* vv   = ws + 3276800;
  float* attn = ws + 4915200;
  float* out1 = ws + 6553600;            // ends at 8,192,000 floats (32.8 MB)

  float* moe   = q;
  int*   cnt   = (int*)(kk + 51200);     // 8 ints
  float* imp   = kk + 51208;             // 8 floats
  float* loadv = kk + 51216;             // 8 floats
  int*   etok  = (int*)(kk + 51224);     // E*T ints
  float* egate = kk + 51224 + Ee*Tt;     // E*T floats

  float* out3 = (float*)d_out;
  float* loss = out3 + Tt * Dd;

  qkv_kernel<<<dim3(400, 3), 256, 0, stream>>>(x, Wq, Wk, Wv, q, kk, vv);
  attn_kernel<<<dim3(256, 2), 256, 0, stream>>>(q, kk, vv, attn);
  // q / kk regions are free from here on
  hipMemsetAsync(moe, 0, (size_t)Tt * Dd * sizeof(float), stream);
  hipMemsetAsync(cnt, 0, 24 * sizeof(float), stream);   // cnt+imp+loadv contiguous
  proj_ln1_kernel<<<Tt/2, 256, 0, stream>>>(x, attn, Wo, bo, ln1_g, ln1_b, out1);
  gate_kernel<<<Tt/256, 256, 0, stream>>>(out1, w_gate, cnt, imp, loadv, etok, egate);
  moe_kernel<<<dim3(200, 8), 256, 0, stream>>>(out1, W1, b1, W2, b2, cnt, etok, egate, moe);
  loss_kernel<<<1, 64, 0, stream>>>(imp, loadv, loss);
  ln2_kernel<<<Tt/2, 256, 0, stream>>>(out1, moe, ln2_g, ln2_b, out3);
}

// Round 2
// 209.186 us; speedup vs baseline: 1.5369x; 1.5369x over previous
//
#include <hip/hip_runtime.h>
#include <math.h>

#define Bb 32
#define Nn 400
#define Dd 128
#define Hh 8
#define QKd 16
#define FFd 512
#define Ee 8
#define Tt (Bb*Nn)   // 12800

typedef __attribute__((ext_vector_type(8))) __bf16 bf16x8;
typedef __attribute__((ext_vector_type(4))) float f32x4;

__device__ __forceinline__ short f2bf(float f){
  union { float f; unsigned u; } v; v.f = f;
  unsigned r = v.u + 0x7FFFu + ((v.u >> 16) & 1u);
  return (short)(r >> 16);
}
__device__ __forceinline__ unsigned pack2bf(float a, float b){
  return (unsigned)(unsigned short)f2bf(a) | ((unsigned)(unsigned short)f2bf(b) << 16);
}

// ---------------- K1: QKV projection ----------------
__global__ __launch_bounds__(256) void qkv_kernel(const float* __restrict__ x,
    const float* __restrict__ Wq, const float* __restrict__ Wk, const float* __restrict__ Wv,
    float* __restrict__ q, float* __restrict__ k, float* __restrict__ v)
{
  __shared__ float xs[32][128];
  const int tid = threadIdx.x;
  const int t0 = blockIdx.x * 32;
  const int sel = blockIdx.y;
  const float* __restrict__ W = (sel == 0) ? Wq : (sel == 1) ? Wk : Wv;
  float* __restrict__ O = (sel == 0) ? q : (sel == 1) ? k : v;

  #pragma unroll
  for (int it = 0; it < 16; ++it) {
    int lin = it * 256 + tid;
    int r = lin >> 7, c = lin & 127;
    xs[r][c] = x[(t0 + r) * Dd + c];
  }
  __syncthreads();

  const int c = tid & 127;
  const int rb = (tid >> 7) * 16;
  float acc[16];
  #pragma unroll
  for (int r = 0; r < 16; ++r) acc[r] = 0.f;

  for (int d4 = 0; d4 < 32; ++d4) {
    float w0 = W[(d4*4+0)*128 + c];
    float w1 = W[(d4*4+1)*128 + c];
    float w2 = W[(d4*4+2)*128 + c];
    float w3 = W[(d4*4+3)*128 + c];
    #pragma unroll
    for (int r = 0; r < 16; ++r) {
      float4 xv = *(const float4*)&xs[rb + r][d4*4];
      acc[r] += xv.x*w0 + xv.y*w1 + xv.z*w2 + xv.w*w3;
    }
  }
  const int h = c >> 4, j = c & 15;
  #pragma unroll
  for (int r = 0; r < 16; ++r) {
    int t = t0 + rb + r;
    int b = t / Nn, n = t % Nn;
    O[((b*Hh + h)*Nn + n)*QKd + j] = acc[r];
  }
}

// ---------------- K2: attention (online softmax) ----------------
__global__ __launch_bounds__(256) void attn_kernel(const float* __restrict__ q,
    const float* __restrict__ k, const float* __restrict__ v, float* __restrict__ attn)
{
  __shared__ float ks[Nn * QKd];
  __shared__ float vs[Nn * QKd];
  const int tid = threadIdx.x;
  const int bh = blockIdx.x;
  const int base = bh * Nn * QKd;

  #pragma unroll
  for (int it = 0; it < 25; ++it) {
    int lin = it * 256 + tid;
    ks[lin] = k[base + lin];
    vs[lin] = v[base + lin];
  }
  __syncthreads();

  if (tid >= 200) return;
  const int i = blockIdx.y * 200 + tid;

  float qr[16];
  const float4* qp = (const float4*)&q[base + i * QKd];
  #pragma unroll
  for (int jj = 0; jj < 4; ++jj) {
    float4 qv = qp[jj];
    qr[jj*4+0] = qv.x; qr[jj*4+1] = qv.y; qr[jj*4+2] = qv.z; qr[jj*4+3] = qv.w;
  }

  float m = -INFINITY, l = 0.f;
  float acc[16];
  #pragma unroll
  for (int jj = 0; jj < 16; ++jj) acc[jj] = 0.f;

  for (int mm = 0; mm < Nn; ++mm) {
    const float* kr = &ks[mm * QKd];
    float s = 0.f;
    #pragma unroll
    for (int jj = 0; jj < 16; ++jj) s += qr[jj] * kr[jj];
    s *= 0.25f;
    float mn = fmaxf(m, s);
    float corr = __expf(m - mn);
    float p = __expf(s - mn);
    l = l * corr + p;
    const float* vr = &vs[mm * QKd];
    #pragma unroll
    for (int jj = 0; jj < 16; ++jj) acc[jj] = acc[jj] * corr + p * vr[jj];
    m = mn;
  }
  const int b = bh >> 3, h = bh & 7;
  const int t = b * Nn + i;
  float inv = 1.f / l;
  #pragma unroll
  for (int jj = 0; jj < 16; ++jj) attn[t * Dd + h * QKd + jj] = acc[jj] * inv;
}

// ---------------- K3: output proj + residual + LN1 ----------------
__global__ __launch_bounds__(256) void proj_ln1_kernel(const float* __restrict__ x,
    const float* __restrict__ attn, const float* __restrict__ Wo, const float* __restrict__ bo,
    const float* __restrict__ g, const float* __restrict__ bb, float* __restrict__ out1)
{
  __shared__ float arow[2][128];
  __shared__ float red[8];
  const int tid = threadIdx.x;
  const int half = tid >> 7;
  const int j = tid & 127;
  const int t = blockIdx.x * 2 + half;
  arow[half][j] = attn[t * Dd + j];
  __syncthreads();

  float acc = bo[j];
  for (int d4 = 0; d4 < 32; ++d4) {
    float4 av = *(const float4*)&arow[half][d4*4];
    acc += av.x * Wo[(d4*4+0)*Dd + j] + av.y * Wo[(d4*4+1)*Dd + j]
         + av.z * Wo[(d4*4+2)*Dd + j] + av.w * Wo[(d4*4+3)*Dd + j];
  }
  float r = x[t * Dd + j] + acc;

  float s = r;
  #pragma unroll
  for (int off = 32; off > 0; off >>= 1) s += __shfl_xor(s, off, 64);
  const int wid = tid >> 6;
  if ((tid & 63) == 0) red[wid] = s;
  __syncthreads();
  float mean = (red[half*2] + red[half*2+1]) * (1.f/128.f);
  float dv = r - mean;
  float s2 = dv * dv;
  #pragma unroll
  for (int off = 32; off > 0; off >>= 1) s2 += __shfl_xor(s2, off, 64);
  if ((tid & 63) == 0) red[4 + wid] = s2;
  __syncthreads();
  float var = (red[4 + half*2] + red[4 + half*2+1]) * (1.f/128.f);
  out1[t * Dd + j] = dv * rsqrtf(var + 1e-5f) * g[j] + bb[j];
}

// ---------------- K4: gating + top-2 + compaction ----------------
__global__ __launch_bounds__(256) void gate_kernel(const float* __restrict__ out1,
    const float* __restrict__ w_gate,
    int* __restrict__ cnt, float* __restrict__ imp, float* __restrict__ loadv,
    int* __restrict__ etok, float* __restrict__ egate)
{
  __shared__ float wg[128 * 8];
  __shared__ float s_imp[8], s_load[8];
  __shared__ int s_cnt[8], s_base[8];
  const int tid = threadIdx.x;
  #pragma unroll
  for (int it = 0; it < 4; ++it) wg[it * 256 + tid] = w_gate[it * 256 + tid];
  if (tid < 8) { s_imp[tid] = 0.f; s_load[tid] = 0.f; s_cnt[tid] = 0; }
  __syncthreads();

  const int t = blockIdx.x * 256 + tid;
  float lg[8];
  #pragma unroll
  for (int e = 0; e < 8; ++e) lg[e] = 0.f;
  for (int d4 = 0; d4 < 32; ++d4) {
    float4 xv = *(const float4*)&out1[t * Dd + d4*4];
    #pragma unroll
    for (int e = 0; e < 8; ++e)
      lg[e] += xv.x * wg[(d4*4+0)*8+e] + xv.y * wg[(d4*4+1)*8+e]
             + xv.z * wg[(d4*4+2)*8+e] + xv.w * wg[(d4*4+3)*8+e];
  }
  int i0 = 0; float v0 = lg[0];
  #pragma unroll
  for (int e = 1; e < 8; ++e) if (lg[e] > v0) { v0 = lg[e]; i0 = e; }
  int i1 = -1; float v1 = -INFINITY;
  #pragma unroll
  for (int e = 0; e < 8; ++e) if (e != i0 && lg[e] > v1) { v1 = lg[e]; i1 = e; }
  float g0 = 1.f / (1.f + __expf(v1 - v0));
  float g1 = 1.f - g0;

  atomicAdd(&s_imp[i0], g0);  atomicAdd(&s_imp[i1], g1);
  atomicAdd(&s_load[i0], 1.f); atomicAdd(&s_load[i1], 1.f);
  int p0 = atomicAdd(&s_cnt[i0], 1);
  int p1 = atomicAdd(&s_cnt[i1], 1);
  __syncthreads();
  if (tid < 8) {
    s_base[tid] = atomicAdd(&cnt[tid], s_cnt[tid]);
    atomicAdd(&imp[tid], s_imp[tid]);
    atomicAdd(&loadv[tid], s_load[tid]);
  }
  __syncthreads();
  int o0 = i0 * Tt + s_base[i0] + p0;
  etok[o0] = t;               egate[o0] = g0;   // slot 0
  int o1 = i1 * Tt + s_base[i1] + p1;
  etok[o1] = t | (1 << 30);   egate[o1] = g1;   // slot 1
}

// ---------------- K5: moe aux loss ----------------
__global__ void loss_kernel(const float* __restrict__ imp, const float* __restrict__ loadv,
                            float* __restrict__ out_loss)
{
  if (threadIdx.x == 0) {
    float m1 = 0.f;
    for (int e = 0; e < 8; ++e) m1 += imp[e];
    m1 *= 0.125f;
    float v1 = 0.f;
    for (int e = 0; e < 8; ++e) { float d = imp[e] - m1; v1 += d * d; }
    v1 *= 0.125f;
    float c1 = v1 / (m1 * m1 + 1e-10f);
    float m2 = 0.f;
    for (int e = 0; e < 8; ++e) m2 += loadv[e];
    m2 *= 0.125f;
    float v2 = 0.f;
    for (int e = 0; e < 8; ++e) { float d = loadv[e] - m2; v2 += d * d; }
    v2 *= 0.125f;
    float c2 = v2 / (m2 * m2 + 1e-10f);
    out_loss[0] = (c1 + c2) * 0.01f;
  }
}

// ---------------- K_T: transpose + cast to bf16 ----------------
// in: [E][R][C] f32 -> out: [E][C][R] bf16
__global__ __launch_bounds__(256) void transpose_bf16_kernel(const float* __restrict__ in,
    short* __restrict__ out, int R, int C)
{
  __shared__ float tile[32][33];
  const int e = blockIdx.y;
  const int nCt = C >> 5;
  const int c0 = (blockIdx.x % nCt) << 5;
  const int r0 = (blockIdx.x / nCt) << 5;
  const int tx = threadIdx.x & 31, ty = threadIdx.x >> 5;
  const float* ip = in + (size_t)e * R * C;
  short* op = out + (size_t)e * R * C;
  #pragma unroll
  for (int i = 0; i < 4; ++i)
    tile[ty + 8*i][tx] = ip[(size_t)(r0 + ty + 8*i) * C + c0 + tx];
  __syncthreads();
  #pragma unroll
  for (int i = 0; i < 4; ++i)
    op[(size_t)(c0 + ty + 8*i) * R + r0 + tx] = f2bf(tile[tx][ty + 8*i]);
}

// ---------------- K6: grouped sparse MoE FFN (MFMA bf16) ----------------
// grid (200, 8): blockIdx.y = expert, blockIdx.x = 64-token tile.
// W1t: [E][FF][D] bf16, W2t: [E][D][FF] bf16 (both K-contiguous for A-frags).
__global__ __launch_bounds__(256) void moe_kernel(const float* __restrict__ out1,
    const short* __restrict__ W1t, const float* __restrict__ b1,
    const short* __restrict__ W2t, const float* __restrict__ b2,
    const int* __restrict__ cnt, const int* __restrict__ etok, const float* __restrict__ egate,
    float* __restrict__ moe0, float* __restrict__ moe1)
{
  __shared__ short xs[64][136];   // tokens x D (bf16, padded stride)
  __shared__ short hs[64][136];   // tokens x FF-chunk (bf16)
  __shared__ int els[64];
  __shared__ float gls[64];

  const int e = blockIdx.y;
  const int count = cnt[e];
  const int t0 = blockIdx.x * 64;
  if (t0 >= count) return;
  const int nt = min(64, count - t0);
  const int tid = threadIdx.x;

  if (tid < 64) {
    int idx = (tid < nt) ? tid : 0;
    els[tid] = etok[e * Tt + t0 + idx];
    gls[tid] = (tid < nt) ? egate[e * Tt + t0 + tid] : 0.f;
  }
  __syncthreads();

  // stage gathered X tile (64 x 128) as bf16
  #pragma unroll
  for (int it = 0; it < 8; ++it) {
    int lin = it * 256 + tid;          // 0..2047
    int r = lin >> 5;                  // 0..63
    int c4 = (lin & 31) << 2;          // 0..124
    int tok = els[r] & 0x3FFFFFFF;
    float4 xv = *(const float4*)&out1[(size_t)tok * Dd + c4];
    uint2 p;
    p.x = pack2bf(xv.x, xv.y);
    p.y = pack2bf(xv.z, xv.w);
    *(uint2*)&xs[r][c4] = p;
  }
  __syncthreads();

  const int lane = tid & 63;
  const int w = tid >> 6;          // wave 0..3
  const int l15 = lane & 15;
  const int l4 = lane >> 4;        // 0..3

  f32x4 zero4 = {0.f, 0.f, 0.f, 0.f};
  f32x4 y[2][4];
  #pragma unroll
  for (int dt = 0; dt < 2; ++dt)
    #pragma unroll
    for (int mt = 0; mt < 4; ++mt) y[dt][mt] = zero4;

  const short* W1p = W1t + (size_t)e * FFd * Dd;
  const short* W2p = W2t + (size_t)e * Dd * FFd;

  for (int ch = 0; ch < 4; ++ch) {
    // ---- GEMM1: H^T[ff][m] = sum_d W1t[ff][d] * X[m][d]
    f32x4 h[2][4];
    #pragma unroll
    for (int ft = 0; ft < 2; ++ft)
      #pragma unroll
      for (int mt = 0; mt < 4; ++mt) h[ft][mt] = zero4;

    #pragma unroll
    for (int kt = 0; kt < 4; ++kt) {
      bf16x8 a0 = *(const bf16x8*)&W1p[(size_t)(ch*128 + w*32 + 0*16 + l15) * Dd + kt*32 + l4*8];
      bf16x8 a1 = *(const bf16x8*)&W1p[(size_t)(ch*128 + w*32 + 1*16 + l15) * Dd + kt*32 + l4*8];
      bf16x8 bm[4];
      #pragma unroll
      for (int mt = 0; mt < 4; ++mt)
        bm[mt] = *(const bf16x8*)&xs[mt*16 + l15][kt*32 + l4*8];
      #pragma unroll
      for (int mt = 0; mt < 4; ++mt) {
        h[0][mt] = __builtin_amdgcn_mfma_f32_16x16x32_bf16(a0, bm[mt], h[0][mt], 0, 0, 0);
        h[1][mt] = __builtin_amdgcn_mfma_f32_16x16x32_bf16(a1, bm[mt], h[1][mt], 0, 0, 0);
      }
    }

    // bias + relu -> hs (bf16)
    float4 b1v0 = *(const float4*)&b1[e*FFd + ch*128 + w*32 + 0*16 + l4*4];
    float4 b1v1 = *(const float4*)&b1[e*FFd + ch*128 + w*32 + 1*16 + l4*4];
    __syncthreads();   // prior GEMM2 reads of hs are done
    #pragma unroll
    for (int mt = 0; mt < 4; ++mt) {
      uint2 p0, p1;
      p0.x = pack2bf(fmaxf(h[0][mt][0] + b1v0.x, 0.f), fmaxf(h[0][mt][1] + b1v0.y, 0.f));
      p0.y = pack2bf(fmaxf(h[0][mt][2] + b1v0.z, 0.f), fmaxf(h[0][mt][3] + b1v0.w, 0.f));
      *(uint2*)&hs[mt*16 + l15][w*32 + 0*16 + l4*4] = p0;
      p1.x = pack2bf(fmaxf(h[1][mt][0] + b1v1.x, 0.f), fmaxf(h[1][mt][1] + b1v1.y, 0.f));
      p1.y = pack2bf(fmaxf(h[1][mt][2] + b1v1.z, 0.f), fmaxf(h[1][mt][3] + b1v1.w, 0.f));
      *(uint2*)&hs[mt*16 + l15][w*32 + 1*16 + l4*4] = p1;
    }
    __syncthreads();

    // ---- GEMM2: Y^T[d][m] += sum_ff W2t[d][ff] * H[m][ff]
    #pragma unroll
    for (int kt = 0; kt < 4; ++kt) {
      bf16x8 a0 = *(const bf16x8*)&W2p[(size_t)(w*32 + 0*16 + l15) * FFd + ch*128 + kt*32 + l4*8];
      bf16x8 a1 = *(const bf16x8*)&W2p[(size_t)(w*32 + 1*16 + l15) * FFd + ch*128 + kt*32 + l4*8];
      bf16x8 bm[4];
      #pragma unroll
      for (int mt = 0; mt < 4; ++mt)
        bm[mt] = *(const bf16x8*)&hs[mt*16 + l15][kt*32 + l4*8];
      #pragma unroll
      for (int mt = 0; mt < 4; ++mt) {
        y[0][mt] = __builtin_amdgcn_mfma_f32_16x16x32_bf16(a0, bm[mt], y[0][mt], 0, 0, 0);
        y[1][mt] = __builtin_amdgcn_mfma_f32_16x16x32_bf16(a1, bm[mt], y[1][mt], 0, 0, 0);
      }
    }
  }

  // epilogue: slot-routed plain float4 stores (no atomics)
  float4 b2v[2];
  b2v[0] = *(const float4*)&b2[e*Dd + w*32 + 0*16 + l4*4];
  b2v[1] = *(const float4*)&b2[e*Dd + w*32 + 1*16 + l4*4];
  #pragma unroll
  for (int mt = 0; mt < 4; ++mt) {
    int m = mt*16 + l15;
    if (m < nt) {
      int raw = els[m];
      int t = raw & 0x3FFFFFFF;
      float g = gls[m];
      float* basep = (raw & (1 << 30)) ? moe1 : moe0;
      #pragma unroll
      for (int dt = 0; dt < 2; ++dt) {
        float4 v;
        v.x = g * (y[dt][mt][0] + ((dt == 0) ? b2v[0].x : b2v[1].x));
        v.y = g * (y[dt][mt][1] + ((dt == 0) ? b2v[0].y : b2v[1].y));
        v.z = g * (y[dt][mt][2] + ((dt == 0) ? b2v[0].z : b2v[1].z));
        v.w = g * (y[dt][mt][3] + ((dt == 0) ? b2v[0].w : b2v[1].w));
        *(float4*)&basep[(size_t)t * Dd + w*32 + dt*16 + l4*4] = v;
      }
    }
  }
}

// ---------------- K7: residual + LN2 -> d_out ----------------
__global__ __launch_bounds__(256) void ln2_kernel(const float* __restrict__ out1,
    const float* __restrict__ moe0, const float* __restrict__ moe1,
    const float* __restrict__ g, const float* __restrict__ bb,
    float* __restrict__ out)
{
  __shared__ float red[8];
  const int tid = threadIdx.x;
  const int half = tid >> 7;
  const int j = tid & 127;
  const int t = blockIdx.x * 2 + half;
  float r = out1[t * Dd + j] + moe0[t * Dd + j] + moe1[t * Dd + j];

  float s = r;
  #pragma unroll
  for (int off = 32; off > 0; off >>= 1) s += __shfl_xor(s, off, 64);
  const int wid = tid >> 6;
  if ((tid & 63) == 0) red[wid] = s;
  __syncthreads();
  float mean = (red[half*2] + red[half*2+1]) * (1.f/128.f);
  float dv = r - mean;
  float s2 = dv * dv;
  #pragma unroll
  for (int off = 32; off > 0; off >>= 1) s2 += __shfl_xor(s2, off, 64);
  if ((tid & 63) == 0) red[4 + wid] = s2;
  __syncthreads();
  float var = (red[4 + half*2] + red[4 + half*2+1]) * (1.f/128.f);
  out[t * Dd + j] = dv * rsqrtf(var + 1e-5f) * g[j] + bb[j];
}

extern "C" void kernel_launch(void* const* d_in, const int* in_sizes, int n_in,
                              void* d_out, int out_size, void* d_ws, size_t ws_size,
                              hipStream_t stream)
{
  (void)in_sizes; (void)n_in; (void)out_size; (void)ws_size;
  const float* x      = (const float*)d_in[0];
  const float* Wq     = (const float*)d_in[1];
  const float* Wk     = (const float*)d_in[2];
  const float* Wv     = (const float*)d_in[3];
  const float* Wo     = (const float*)d_in[4];
  const float* bo     = (const float*)d_in[5];
  const float* ln1_g  = (const float*)d_in[6];
  const float* ln1_b  = (const float*)d_in[7];
  const float* w_gate = (const float*)d_in[8];
  const float* W1     = (const float*)d_in[9];
  const float* b1     = (const float*)d_in[10];
  const float* W2     = (const float*)d_in[11];
  const float* b2     = (const float*)d_in[12];
  const float* ln2_g  = (const float*)d_in[13];
  const float* ln2_b  = (const float*)d_in[14];

  float* ws   = (float*)d_ws;
  float* q    = ws + 0;                  // 1,638,400 floats; reused as moe slot-0 accumulator
  float* kk   = ws + 1638400;            // reused for gating/compaction after attention
  float* vv   = ws + 3276800;            // reused for bf16 transposed weights after attention
  float* attn = ws + 4915200;            // reused as moe slot-1 accumulator after proj_ln1
  float* out1 = ws + 6553600;            // ends at 8,192,000 floats (32.8 MB)

  float* moe0  = q;
  float* moe1  = attn;
  int*   cnt   = (int*)(kk + 51200);     // 8 ints
  float* imp   = kk + 51208;             // 8 floats
  float* loadv = kk + 51216;             // 8 floats
  int*   etok  = (int*)(kk + 51224);     // E*T ints
  float* egate = kk + 51224 + Ee*Tt;     // E*T floats
  short* W1t   = (short*)vv;             // [E][FF][D] bf16, 1 MB
  short* W2t   = (short*)(vv + 262144);  // [E][D][FF] bf16, 1 MB

  float* out3 = (float*)d_out;
  float* loss = out3 + Tt * Dd;

  qkv_kernel<<<dim3(400, 3), 256, 0, stream>>>(x, Wq, Wk, Wv, q, kk, vv);
  attn_kernel<<<dim3(256, 2), 256, 0, stream>>>(q, kk, vv, attn);
  // q/kk/vv regions free from here on
  transpose_bf16_kernel<<<dim3(64, 8), 256, 0, stream>>>(W1, W1t, Dd, FFd);   // -> [FF][D]
  transpose_bf16_kernel<<<dim3(64, 8), 256, 0, stream>>>(W2, W2t, FFd, Dd);   // -> [D][FF]
  hipMemsetAsync(cnt, 0, 24 * sizeof(float), stream);   // cnt+imp+loadv contiguous
  proj_ln1_kernel<<<Tt/2, 256, 0, stream>>>(x, attn, Wo, bo, ln1_g, ln1_b, out1);
  gate_kernel<<<Tt/256, 256, 0, stream>>>(out1, w_gate, cnt, imp, loadv, etok, egate);
  moe_kernel<<<dim3(200, 8), 256, 0, stream>>>(out1, W1t, b1, W2t, b2, cnt, etok, egate, moe0, moe1);
  loss_kernel<<<1, 64, 0, stream>>>(imp, loadv, loss);
  ln2_kernel<<<Tt/2, 256, 0, stream>>>(out1, moe0, moe1, ln2_g, ln2_b, out3);
}

// Round 3
// 152.551 us; speedup vs baseline: 2.1074x; 1.3713x over previous
//
#include <hip/hip_runtime.h>
#include <math.h>

#define Bb 32
#define Nn 400
#define Dd 128
#define Hh 8
#define QKd 16
#define FFd 512
#define Ee 8
#define Tt (Bb*Nn)   // 12800
#define KPAD 424     // VT row stride (bf16 elems)
#define PPAD 136     // P row stride (bf16 elems)

typedef __attribute__((ext_vector_type(8))) __bf16 bf16x8;
typedef __attribute__((ext_vector_type(4))) float f32x4;

#if defined(__has_builtin)
#if __has_builtin(__builtin_amdgcn_exp2f)
#define EXP2(x) __builtin_amdgcn_exp2f(x)
#endif
#endif
#ifndef EXP2
#define EXP2(x) __expf((x) * 0.69314718f)
#endif

__device__ __forceinline__ short f2bf(float f){
  union { float f; unsigned u; } v; v.f = f;
  unsigned r = v.u + 0x7FFFu + ((v.u >> 16) & 1u);
  return (short)(r >> 16);
}
__device__ __forceinline__ unsigned pack2bf(float a, float b){
  return (unsigned)(unsigned short)f2bf(a) | ((unsigned)(unsigned short)f2bf(b) << 16);
}

// ---------------- K1: QKV projection (bf16 outputs, MFMA-ready layouts) ----------------
// q,k: [BH][400][32] bf16 (dims 16..31 zero; q pre-scaled by 0.25*log2e). v: [BH][400][16] bf16.
__global__ __launch_bounds__(256) void qkv_kernel(const float* __restrict__ x,
    const float* __restrict__ Wq, const float* __restrict__ Wk, const float* __restrict__ Wv,
    short* __restrict__ q, short* __restrict__ k, short* __restrict__ v)
{
  __shared__ float xs[32][128];
  const int tid = threadIdx.x;
  const int t0 = blockIdx.x * 32;
  const int sel = blockIdx.y;
  const float* __restrict__ W = (sel == 0) ? Wq : (sel == 1) ? Wk : Wv;

  #pragma unroll
  for (int it = 0; it < 16; ++it) {
    int lin = it * 256 + tid;
    int r = lin >> 7, c = lin & 127;
    xs[r][c] = x[(t0 + r) * Dd + c];
  }
  __syncthreads();

  const int c = tid & 127;
  const int rb = (tid >> 7) * 16;
  float acc[16];
  #pragma unroll
  for (int r = 0; r < 16; ++r) acc[r] = 0.f;

  for (int d4 = 0; d4 < 32; ++d4) {
    float w0 = W[(d4*4+0)*128 + c];
    float w1 = W[(d4*4+1)*128 + c];
    float w2 = W[(d4*4+2)*128 + c];
    float w3 = W[(d4*4+3)*128 + c];
    #pragma unroll
    for (int r = 0; r < 16; ++r) {
      float4 xv = *(const float4*)&xs[rb + r][d4*4];
      acc[r] += xv.x*w0 + xv.y*w1 + xv.z*w2 + xv.w*w3;
    }
  }
  const int h = c >> 4, j = c & 15;
  #pragma unroll
  for (int r = 0; r < 16; ++r) {
    int t = t0 + rb + r;
    int b = t / Nn, n = t % Nn;
    size_t bhn = (size_t)(b*Hh + h)*Nn + n;
    if (sel == 0) {          // q: scaled so softmax is exp2(S)
      q[bhn*32 + j] = f2bf(acc[r] * 0.36067376f);   // 0.25 * log2(e)
      q[bhn*32 + j + 16] = 0;
    } else if (sel == 1) {
      k[bhn*32 + j] = f2bf(acc[r]);
      k[bhn*32 + j + 16] = 0;
    } else {
      v[bhn*16 + j] = f2bf(acc[r]);
    }
  }
}

// ---------------- K2: attention via MFMA ----------------
// grid 1280 (= 256 bh x 5 q-groups), block 320 (5 waves; 1 q-tile of 16 rows per wave).
__global__ __launch_bounds__(320) void attn_kernel(const short* __restrict__ q,
    const short* __restrict__ k, const short* __restrict__ v, float* __restrict__ attn)
{
  __shared__ short K_lds[400 * 32];     // 25600 B
  __shared__ short VT[16 * KPAD];       // 13568 B (keys 400..415 zeroed)
  __shared__ short P[5][16 * PPAD];     // 21760 B (per-wave)
  const int tid = threadIdx.x;
  const int bh = blockIdx.x / 5;
  const int qb = blockIdx.x % 5;

  // stage K [400][32] bf16 (already padded in global)
  {
    const uint4* kg = (const uint4*)(k + (size_t)bh * 400 * 32);
    uint4* kl = (uint4*)K_lds;
    #pragma unroll
    for (int it = 0; it < 5; ++it) kl[it*320 + tid] = kg[it*320 + tid];
  }
  // stage V^T [16][KPAD]
  {
    const unsigned* vg = (const unsigned*)(v + (size_t)bh * 400 * 16);
    #pragma unroll
    for (int it = 0; it < 10; ++it) {
      int lin = it*320 + tid;
      int key = lin >> 3, dp = lin & 7;
      unsigned pv = vg[key*8 + dp];
      VT[(2*dp)  * KPAD + key] = (short)(pv & 0xffffu);
      VT[(2*dp+1)* KPAD + key] = (short)(pv >> 16);
    }
    if (tid < 256) {   // zero pad keys 400..415
      int d = tid >> 4, key = 400 + (tid & 15);
      VT[d*KPAD + key] = 0;
    }
  }
  __syncthreads();

  const int w = tid >> 6, lane = tid & 63;
  const int l15 = lane & 15, g = lane >> 4;
  const int q0 = (qb*5 + w) * 16;

  const bf16x8 qf = *(const bf16x8*)&q[((size_t)bh*400 + q0 + l15)*32 + 8*g];
  short* Pw = &P[w][0];

  f32x4 zero4 = {0.f, 0.f, 0.f, 0.f};
  f32x4 o = zero4;
  float lsum = 0.f;

  for (int cc = 0; cc < 4; ++cc) {
    const int ntl = (cc < 3) ? 8 : 1;   // key tiles this chunk (chunk 3: only keys 384..399)
    for (int t = 0; t < ntl; ++t) {
      int kt = cc*8 + t;
      bf16x8 kf = *(const bf16x8*)&K_lds[(kt*16 + l15)*32 + 8*g];
      f32x4 s = __builtin_amdgcn_mfma_f32_16x16x32_bf16(kf, qf, zero4, 0, 0, 0);
      float p0 = EXP2(s[0]);
      float p1 = EXP2(s[1]);
      float p2 = EXP2(s[2]);
      float p3 = EXP2(s[3]);
      lsum += (p0 + p1) + (p2 + p3);
      uint2 pk;
      pk.x = pack2bf(p0, p1);
      pk.y = pack2bf(p2, p3);
      *(uint2*)&Pw[l15*PPAD + t*16 + 4*g] = pk;   // P[q][key]
    }
    if (cc == 3) {   // keys 400..415 -> P = 0
      uint2 z; z.x = 0u; z.y = 0u;
      *(uint2*)&Pw[l15*PPAD + 16 + 4*g] = z;
    }
    const int nm = (cc < 3) ? 4 : 1;
    for (int m = 0; m < nm; ++m) {
      bf16x8 vf = *(const bf16x8*)&VT[l15*KPAD + cc*128 + m*32 + 8*g];
      bf16x8 pf = *(const bf16x8*)&Pw[l15*PPAD + m*32 + 8*g];
      o = __builtin_amdgcn_mfma_f32_16x16x32_bf16(vf, pf, o, 0, 0, 0);
    }
  }

  // row-sum across the 4 lane-groups sharing this q (xor bits 4,5)
  lsum += __shfl_xor(lsum, 16, 64);
  lsum += __shfl_xor(lsum, 32, 64);
  float inv = 1.f / lsum;

  const int b = bh >> 3, h = bh & 7;
  float4 ov;
  ov.x = o[0]*inv; ov.y = o[1]*inv; ov.z = o[2]*inv; ov.w = o[3]*inv;
  *(float4*)&attn[((size_t)b*Nn + q0 + l15)*Dd + h*16 + 4*g] = ov;
}

// ---------------- K3: output proj + residual + LN1 ----------------
__global__ __launch_bounds__(256) void proj_ln1_kernel(const float* __restrict__ x,
    const float* __restrict__ attn, const float* __restrict__ Wo, const float* __restrict__ bo,
    const float* __restrict__ g, const float* __restrict__ bb, float* __restrict__ out1)
{
  __shared__ float arow[2][128];
  __shared__ float red[8];
  const int tid = threadIdx.x;
  const int half = tid >> 7;
  const int j = tid & 127;
  const int t = blockIdx.x * 2 + half;
  arow[half][j] = attn[t * Dd + j];
  __syncthreads();

  float acc = bo[j];
  for (int d4 = 0; d4 < 32; ++d4) {
    float4 av = *(const float4*)&arow[half][d4*4];
    acc += av.x * Wo[(d4*4+0)*Dd + j] + av.y * Wo[(d4*4+1)*Dd + j]
         + av.z * Wo[(d4*4+2)*Dd + j] + av.w * Wo[(d4*4+3)*Dd + j];
  }
  float r = x[t * Dd + j] + acc;

  float s = r;
  #pragma unroll
  for (int off = 32; off > 0; off >>= 1) s += __shfl_xor(s, off, 64);
  const int wid = tid >> 6;
  if ((tid & 63) == 0) red[wid] = s;
  __syncthreads();
  float mean = (red[half*2] + red[half*2+1]) * (1.f/128.f);
  float dv = r - mean;
  float s2 = dv * dv;
  #pragma unroll
  for (int off = 32; off > 0; off >>= 1) s2 += __shfl_xor(s2, off, 64);
  if ((tid & 63) == 0) red[4 + wid] = s2;
  __syncthreads();
  float var = (red[4 + half*2] + red[4 + half*2+1]) * (1.f/128.f);
  out1[t * Dd + j] = dv * rsqrtf(var + 1e-5f) * g[j] + bb[j];
}

// ---------------- K4: gating + top-2 + compaction ----------------
__global__ __launch_bounds__(256) void gate_kernel(const float* __restrict__ out1,
    const float* __restrict__ w_gate,
    int* __restrict__ cnt, float* __restrict__ imp, float* __restrict__ loadv,
    int* __restrict__ etok, float* __restrict__ egate)
{
  __shared__ float wg[128 * 8];
  __shared__ float s_imp[8], s_load[8];
  __shared__ int s_cnt[8], s_base[8];
  const int tid = threadIdx.x;
  #pragma unroll
  for (int it = 0; it < 4; ++it) wg[it * 256 + tid] = w_gate[it * 256 + tid];
  if (tid < 8) { s_imp[tid] = 0.f; s_load[tid] = 0.f; s_cnt[tid] = 0; }
  __syncthreads();

  const int t = blockIdx.x * 256 + tid;
  float lg[8];
  #pragma unroll
  for (int e = 0; e < 8; ++e) lg[e] = 0.f;
  for (int d4 = 0; d4 < 32; ++d4) {
    float4 xv = *(const float4*)&out1[t * Dd + d4*4];
    #pragma unroll
    for (int e = 0; e < 8; ++e)
      lg[e] += xv.x * wg[(d4*4+0)*8+e] + xv.y * wg[(d4*4+1)*8+e]
             + xv.z * wg[(d4*4+2)*8+e] + xv.w * wg[(d4*4+3)*8+e];
  }
  int i0 = 0; float v0 = lg[0];
  #pragma unroll
  for (int e = 1; e < 8; ++e) if (lg[e] > v0) { v0 = lg[e]; i0 = e; }
  int i1 = -1; float v1 = -INFINITY;
  #pragma unroll
  for (int e = 0; e < 8; ++e) if (e != i0 && lg[e] > v1) { v1 = lg[e]; i1 = e; }
  float g0 = 1.f / (1.f + __expf(v1 - v0));
  float g1 = 1.f - g0;

  atomicAdd(&s_imp[i0], g0);  atomicAdd(&s_imp[i1], g1);
  atomicAdd(&s_load[i0], 1.f); atomicAdd(&s_load[i1], 1.f);
  int p0 = atomicAdd(&s_cnt[i0], 1);
  int p1 = atomicAdd(&s_cnt[i1], 1);
  __syncthreads();
  if (tid < 8) {
    s_base[tid] = atomicAdd(&cnt[tid], s_cnt[tid]);
    atomicAdd(&imp[tid], s_imp[tid]);
    atomicAdd(&loadv[tid], s_load[tid]);
  }
  __syncthreads();
  int o0 = i0 * Tt + s_base[i0] + p0;
  etok[o0] = t;               egate[o0] = g0;   // slot 0
  int o1 = i1 * Tt + s_base[i1] + p1;
  etok[o1] = t | (1 << 30);   egate[o1] = g1;   // slot 1
}

// ---------------- K5: moe aux loss ----------------
__global__ void loss_kernel(const float* __restrict__ imp, const float* __restrict__ loadv,
                            float* __restrict__ out_loss)
{
  if (threadIdx.x == 0) {
    float m1 = 0.f;
    for (int e = 0; e < 8; ++e) m1 += imp[e];
    m1 *= 0.125f;
    float v1 = 0.f;
    for (int e = 0; e < 8; ++e) { float d = imp[e] - m1; v1 += d * d; }
    v1 *= 0.125f;
    float c1 = v1 / (m1 * m1 + 1e-10f);
    float m2 = 0.f;
    for (int e = 0; e < 8; ++e) m2 += loadv[e];
    m2 *= 0.125f;
    float v2 = 0.f;
    for (int e = 0; e < 8; ++e) { float d = loadv[e] - m2; v2 += d * d; }
    v2 *= 0.125f;
    float c2 = v2 / (m2 * m2 + 1e-10f);
    out_loss[0] = (c1 + c2) * 0.01f;
  }
}

// ---------------- K_T: transpose + cast to bf16 ----------------
__global__ __launch_bounds__(256) void transpose_bf16_kernel(const float* __restrict__ in,
    short* __restrict__ out, int R, int C)
{
  __shared__ float tile[32][33];
  const int e = blockIdx.y;
  const int nCt = C >> 5;
  const int c0 = (blockIdx.x % nCt) << 5;
  const int r0 = (blockIdx.x / nCt) << 5;
  const int tx = threadIdx.x & 31, ty = threadIdx.x >> 5;
  const float* ip = in + (size_t)e * R * C;
  short* op = out + (size_t)e * R * C;
  #pragma unroll
  for (int i = 0; i < 4; ++i)
    tile[ty + 8*i][tx] = ip[(size_t)(r0 + ty + 8*i) * C + c0 + tx];
  __syncthreads();
  #pragma unroll
  for (int i = 0; i < 4; ++i)
    op[(size_t)(c0 + ty + 8*i) * R + r0 + tx] = f2bf(tile[tx][ty + 8*i]);
}

// ---------------- K6: grouped sparse MoE FFN (MFMA bf16) ----------------
__global__ __launch_bounds__(256) void moe_kernel(const float* __restrict__ out1,
    const short* __restrict__ W1t, const float* __restrict__ b1,
    const short* __restrict__ W2t, const float* __restrict__ b2,
    const int* __restrict__ cnt, const int* __restrict__ etok, const float* __restrict__ egate,
    float* __restrict__ moe0, float* __restrict__ moe1)
{
  __shared__ short xs[64][136];
  __shared__ short hs[64][136];
  __shared__ int els[64];
  __shared__ float gls[64];

  const int e = blockIdx.y;
  const int count = cnt[e];
  const int t0 = blockIdx.x * 64;
  if (t0 >= count) return;
  const int nt = min(64, count - t0);
  const int tid = threadIdx.x;

  if (tid < 64) {
    int idx = (tid < nt) ? tid : 0;
    els[tid] = etok[e * Tt + t0 + idx];
    gls[tid] = (tid < nt) ? egate[e * Tt + t0 + tid] : 0.f;
  }
  __syncthreads();

  #pragma unroll
  for (int it = 0; it < 8; ++it) {
    int lin = it * 256 + tid;
    int r = lin >> 5;
    int c4 = (lin & 31) << 2;
    int tok = els[r] & 0x3FFFFFFF;
    float4 xv = *(const float4*)&out1[(size_t)tok * Dd + c4];
    uint2 p;
    p.x = pack2bf(xv.x, xv.y);
    p.y = pack2bf(xv.z, xv.w);
    *(uint2*)&xs[r][c4] = p;
  }
  __syncthreads();

  const int lane = tid & 63;
  const int w = tid >> 6;
  const int l15 = lane & 15;
  const int l4 = lane >> 4;

  f32x4 zero4 = {0.f, 0.f, 0.f, 0.f};
  f32x4 y[2][4];
  #pragma unroll
  for (int dt = 0; dt < 2; ++dt)
    #pragma unroll
    for (int mt = 0; mt < 4; ++mt) y[dt][mt] = zero4;

  const short* W1p = W1t + (size_t)e * FFd * Dd;
  const short* W2p = W2t + (size_t)e * Dd * FFd;

  for (int ch = 0; ch < 4; ++ch) {
    f32x4 h[2][4];
    #pragma unroll
    for (int ft = 0; ft < 2; ++ft)
      #pragma unroll
      for (int mt = 0; mt < 4; ++mt) h[ft][mt] = zero4;

    #pragma unroll
    for (int kt = 0; kt < 4; ++kt) {
      bf16x8 a0 = *(const bf16x8*)&W1p[(size_t)(ch*128 + w*32 + 0*16 + l15) * Dd + kt*32 + l4*8];
      bf16x8 a1 = *(const bf16x8*)&W1p[(size_t)(ch*128 + w*32 + 1*16 + l15) * Dd + kt*32 + l4*8];
      bf16x8 bm[4];
      #pragma unroll
      for (int mt = 0; mt < 4; ++mt)
        bm[mt] = *(const bf16x8*)&xs[mt*16 + l15][kt*32 + l4*8];
      #pragma unroll
      for (int mt = 0; mt < 4; ++mt) {
        h[0][mt] = __builtin_amdgcn_mfma_f32_16x16x32_bf16(a0, bm[mt], h[0][mt], 0, 0, 0);
        h[1][mt] = __builtin_amdgcn_mfma_f32_16x16x32_bf16(a1, bm[mt], h[1][mt], 0, 0, 0);
      }
    }

    float4 b1v0 = *(const float4*)&b1[e*FFd + ch*128 + w*32 + 0*16 + l4*4];
    float4 b1v1 = *(const float4*)&b1[e*FFd + ch*128 + w*32 + 1*16 + l4*4];
    __syncthreads();
    #pragma unroll
    for (int mt = 0; mt < 4; ++mt) {
      uint2 p0, p1;
      p0.x = pack2bf(fmaxf(h[0][mt][0] + b1v0.x, 0.f), fmaxf(h[0][mt][1] + b1v0.y, 0.f));
      p0.y = pack2bf(fmaxf(h[0][mt][2] + b1v0.z, 0.f), fmaxf(h[0][mt][3] + b1v0.w, 0.f));
      *(uint2*)&hs[mt*16 + l15][w*32 + 0*16 + l4*4] = p0;
      p1.x = pack2bf(fmaxf(h[1][mt][0] + b1v1.x, 0.f), fmaxf(h[1][mt][1] + b1v1.y, 0.f));
      p1.y = pack2bf(fmaxf(h[1][mt][2] + b1v1.z, 0.f), fmaxf(h[1][mt][3] + b1v1.w, 0.f));
      *(uint2*)&hs[mt*16 + l15][w*32 + 1*16 + l4*4] = p1;
    }
    __syncthreads();

    #pragma unroll
    for (int kt = 0; kt < 4; ++kt) {
      bf16x8 a0 = *(const bf16x8*)&W2p[(size_t)(w*32 + 0*16 + l15) * FFd + ch*128 + kt*32 + l4*8];
      bf16x8 a1 = *(const bf16x8*)&W2p[(size_t)(w*32 + 1*16 + l15) * FFd + ch*128 + kt*32 + l4*8];
      bf16x8 bm[4];
      #pragma unroll
      for (int mt = 0; mt < 4; ++mt)
        bm[mt] = *(const bf16x8*)&hs[mt*16 + l15][kt*32 + l4*8];
      #pragma unroll
      for (int mt = 0; mt < 4; ++mt) {
        y[0][mt] = __builtin_amdgcn_mfma_f32_16x16x32_bf16(a0, bm[mt], y[0][mt], 0, 0, 0);
        y[1][mt] = __builtin_amdgcn_mfma_f32_16x16x32_bf16(a1, bm[mt], y[1][mt], 0, 0, 0);
      }
    }
  }

  float4 b2v[2];
  b2v[0] = *(const float4*)&b2[e*Dd + w*32 + 0*16 + l4*4];
  b2v[1] = *(const float4*)&b2[e*Dd + w*32 + 1*16 + l4*4];
  #pragma unroll
  for (int mt = 0; mt < 4; ++mt) {
    int m = mt*16 + l15;
    if (m < nt) {
      int raw = els[m];
      int t = raw & 0x3FFFFFFF;
      float g = gls[m];
      float* basep = (raw & (1 << 30)) ? moe1 : moe0;
      #pragma unroll
      for (int dt = 0; dt < 2; ++dt) {
        float4 v;
        v.x = g * (y[dt][mt][0] + ((dt == 0) ? b2v[0].x : b2v[1].x));
        v.y = g * (y[dt][mt][1] + ((dt == 0) ? b2v[0].y : b2v[1].y));
        v.z = g * (y[dt][mt][2] + ((dt == 0) ? b2v[0].z : b2v[1].z));
        v.w = g * (y[dt][mt][3] + ((dt == 0) ? b2v[0].w : b2v[1].w));
        *(float4*)&basep[(size_t)t * Dd + w*32 + dt*16 + l4*4] = v;
      }
    }
  }
}

// ---------------- K7: residual + LN2 -> d_out ----------------
__global__ __launch_bounds__(256) void ln2_kernel(const float* __restrict__ out1,
    const float* __restrict__ moe0, const float* __restrict__ moe1,
    const float* __restrict__ g, const float* __restrict__ bb,
    float* __restrict__ out)
{
  __shared__ float red[8];
  const int tid = threadIdx.x;
  const int half = tid >> 7;
  const int j = tid & 127;
  const int t = blockIdx.x * 2 + half;
  float r = out1[t * Dd + j] + moe0[t * Dd + j] + moe1[t * Dd + j];

  float s = r;
  #pragma unroll
  for (int off = 32; off > 0; off >>= 1) s += __shfl_xor(s, off, 64);
  const int wid = tid >> 6;
  if ((tid & 63) == 0) red[wid] = s;
  __syncthreads();
  float mean = (red[half*2] + red[half*2+1]) * (1.f/128.f);
  float dv = r - mean;
  float s2 = dv * dv;
  #pragma unroll
  for (int off = 32; off > 0; off >>= 1) s2 += __shfl_xor(s2, off, 64);
  if ((tid & 63) == 0) red[4 + wid] = s2;
  __syncthreads();
  float var = (red[4 + half*2] + red[4 + half*2+1]) * (1.f/128.f);
  out[t * Dd + j] = dv * rsqrtf(var + 1e-5f) * g[j] + bb[j];
}

extern "C" void kernel_launch(void* const* d_in, const int* in_sizes, int n_in,
                              void* d_out, int out_size, void* d_ws, size_t ws_size,
                              hipStream_t stream)
{
  (void)in_sizes; (void)n_in; (void)out_size; (void)ws_size;
  const float* x      = (const float*)d_in[0];
  const float* Wq     = (const float*)d_in[1];
  const float* Wk     = (const float*)d_in[2];
  const float* Wv     = (const float*)d_in[3];
  const float* Wo     = (const float*)d_in[4];
  const float* bo     = (const float*)d_in[5];
  const float* ln1_g  = (const float*)d_in[6];
  const float* ln1_b  = (const float*)d_in[7];
  const float* w_gate = (const float*)d_in[8];
  const float* W1     = (const float*)d_in[9];
  const float* b1     = (const float*)d_in[10];
  const float* W2     = (const float*)d_in[11];
  const float* b2     = (const float*)d_in[12];
  const float* ln2_g  = (const float*)d_in[13];
  const float* ln2_b  = (const float*)d_in[14];

  float* ws   = (float*)d_ws;
  short* q_bf = (short*)ws;              // [256][400][32] bf16 (reused: moe0 after attn)
  short* k_bf = (short*)(ws + 1638400);  // [256][400][32] bf16 (reused: gating bufs after attn)
  short* v_bf = (short*)(ws + 3276800);  // [256][400][16] bf16 (reused: W1t/W2t after attn)
  float* attn = ws + 4915200;            // [12800][128] f32 (reused: moe1 after proj_ln1)
  float* out1 = ws + 6553600;

  float* moe0  = ws;                     // q_bf region
  float* moe1  = attn;
  float* kk    = ws + 1638400;
  int*   cnt   = (int*)(kk + 51200);
  float* imp   = kk + 51208;
  float* loadv = kk + 51216;
  int*   etok  = (int*)(kk + 51224);
  float* egate = kk + 51224 + Ee*Tt;
  short* W1t   = (short*)(ws + 3276800); // [E][FF][D] bf16
  short* W2t   = (short*)(ws + 3538944); // [E][D][FF] bf16

  float* out3 = (float*)d_out;
  float* loss = out3 + Tt * Dd;

  qkv_kernel<<<dim3(400, 3), 256, 0, stream>>>(x, Wq, Wk, Wv, q_bf, k_bf, v_bf);
  attn_kernel<<<1280, 320, 0, stream>>>(q_bf, k_bf, v_bf, attn);
  // q_bf/k_bf/v_bf regions free from here on
  transpose_bf16_kernel<<<dim3(64, 8), 256, 0, stream>>>(W1, W1t, Dd, FFd);   // -> [FF][D]
  transpose_bf16_kernel<<<dim3(64, 8), 256, 0, stream>>>(W2, W2t, FFd, Dd);   // -> [D][FF]
  hipMemsetAsync(cnt, 0, 24 * sizeof(float), stream);
  proj_ln1_kernel<<<Tt/2, 256, 0, stream>>>(x, attn, Wo, bo, ln1_g, ln1_b, out1);
  gate_kernel<<<Tt/256, 256, 0, stream>>>(out1, w_gate, cnt, imp, loadv, etok, egate);
  moe_kernel<<<dim3(200, 8), 256, 0, stream>>>(out1, W1t, b1, W2t, b2, cnt, etok, egate, moe0, moe1);
  loss_kernel<<<1, 64, 0, stream>>>(imp, loadv, loss);
  ln2_kernel<<<Tt/2, 256, 0, stream>>>(out1, moe0, moe1, ln2_g, ln2_b, out3);
}

// Round 6
// 107.853 us; speedup vs baseline: 2.9808x; 1.4144x over previous
//
#include <hip/hip_runtime.h>
#include <math.h>

#define Bb 32
#define Nn 400
#define Dd 128
#define Hh 8
#define QKd 16
#define FFd 512
#define Ee 8
#define Tt (Bb*Nn)   // 12800
#define KPAD 424     // VT row stride (bf16 elems)
#define PPAD 136     // P row stride (bf16 elems)

typedef __attribute__((ext_vector_type(8))) __bf16 bf16x8;
typedef __attribute__((ext_vector_type(4))) float f32x4;

#if defined(__has_builtin)
#if __has_builtin(__builtin_amdgcn_exp2f)
#define EXP2(x) __builtin_amdgcn_exp2f(x)
#endif
#endif
#ifndef EXP2
#define EXP2(x) __expf((x) * 0.69314718f)
#endif

__device__ __forceinline__ short f2bf(float f){
  union { float f; unsigned u; } v; v.f = f;
  unsigned r = v.u + 0x7FFFu + ((v.u >> 16) & 1u);
  return (short)(r >> 16);
}
__device__ __forceinline__ unsigned pack2bf(float a, float b){
  return (unsigned)(unsigned short)f2bf(a) | ((unsigned)(unsigned short)f2bf(b) << 16);
}

// ---------------- K0: prep — all weight transposes (f32 -> bf16^T) + zero gate meta ----------------
__global__ __launch_bounds__(256) void prep_kernel(
    const float* __restrict__ W1, const float* __restrict__ W2, const float* __restrict__ Wo,
    const float* __restrict__ Wq, const float* __restrict__ Wk, const float* __restrict__ Wv,
    short* __restrict__ W1t, short* __restrict__ W2t, short* __restrict__ wo_t,
    short* __restrict__ qkvw, int* __restrict__ gmeta)
{
  const int bid = blockIdx.x;
  if (bid == 0 && threadIdx.x < 24) gmeta[threadIdx.x] = 0;   // cnt[8], imp[8], loadv[8]

  const float* in; short* out; int C, tile;
  if (bid < 512)        { int e = bid >> 6;         tile = bid & 63;          in = W1 + e*65536; out = W1t + e*65536; C = 512; }
  else if (bid < 1024)  { int e = (bid - 512) >> 6; tile = (bid - 512) & 63;  in = W2 + e*65536; out = W2t + e*65536; C = 128; }
  else if (bid < 1040)  { tile = bid - 1024; in = Wo; out = wo_t;          C = 128; }
  else if (bid < 1056)  { tile = bid - 1040; in = Wq; out = qkvw;          C = 128; }
  else if (bid < 1072)  { tile = bid - 1056; in = Wk; out = qkvw + 16384;  C = 128; }
  else                  { tile = bid - 1072; in = Wv; out = qkvw + 32768;  C = 128; }
  const int R = (bid < 512) ? 128 : (bid < 1024 ? 512 : 128);

  __shared__ float t32[32][33];
  const int nCt = C >> 5;
  const int c0 = (tile % nCt) << 5;
  const int r0 = (tile / nCt) << 5;
  const int tx = threadIdx.x & 31, ty = threadIdx.x >> 5;
  #pragma unroll
  for (int i = 0; i < 4; ++i)
    t32[ty + 8*i][tx] = in[(size_t)(r0 + ty + 8*i) * C + c0 + tx];
  __syncthreads();
  #pragma unroll
  for (int i = 0; i < 4; ++i)
    out[(size_t)(c0 + ty + 8*i) * R + r0 + tx] = f2bf(t32[tx][ty + 8*i]);
}

// ---------------- K1: QKV projection via MFMA, split-bf16 activations ----------------
// grid 200, block 256. qkvw: [384][128] bf16. x staged as x_hi + x_lo (bf16 each).
// q,k: [BH][400][32] bf16 (dims 16..31 zero; q pre-scaled). v: [BH][400][16] bf16.
__global__ __launch_bounds__(256) void qkv_kernel(const float* __restrict__ x,
    const short* __restrict__ qkvw,
    short* __restrict__ q, short* __restrict__ k, short* __restrict__ v)
{
  __shared__ short xsh[64][136];
  __shared__ short xsl[64][136];
  const int tid = threadIdx.x;
  const int t0 = blockIdx.x * 64;

  #pragma unroll
  for (int it = 0; it < 8; ++it) {
    int lin = it * 256 + tid;
    int r = lin >> 5;
    int c4 = (lin & 31) << 2;
    float4 xv = *(const float4*)&x[(size_t)(t0 + r) * Dd + c4];
    unsigned h01 = pack2bf(xv.x, xv.y);
    unsigned h23 = pack2bf(xv.z, xv.w);
    union { unsigned u; float f; } ua, ub, uc, ud;
    ua.u = h01 << 16; ub.u = h01 & 0xFFFF0000u;
    uc.u = h23 << 16; ud.u = h23 & 0xFFFF0000u;
    unsigned l01 = pack2bf(xv.x - ua.f, xv.y - ub.f);
    unsigned l23 = pack2bf(xv.z - uc.f, xv.w - ud.f);
    uint2 ph; ph.x = h01; ph.y = h23;
    uint2 pl; pl.x = l01; pl.y = l23;
    *(uint2*)&xsh[r][c4] = ph;
    *(uint2*)&xsl[r][c4] = pl;
  }
  __syncthreads();

  const int lane = tid & 63, w = tid >> 6;
  const int l15 = lane & 15, l4 = lane >> 4;

  f32x4 zero4 = {0.f, 0.f, 0.f, 0.f};
  f32x4 acc[6][4];
  #pragma unroll
  for (int ot = 0; ot < 6; ++ot)
    #pragma unroll
    for (int mt = 0; mt < 4; ++mt) acc[ot][mt] = zero4;

  #pragma unroll
  for (int kt = 0; kt < 4; ++kt) {
    bf16x8 bmh[4], bml[4];
    #pragma unroll
    for (int mt = 0; mt < 4; ++mt) {
      bmh[mt] = *(const bf16x8*)&xsh[mt*16 + l15][kt*32 + l4*8];
      bml[mt] = *(const bf16x8*)&xsl[mt*16 + l15][kt*32 + l4*8];
    }
    #pragma unroll
    for (int ot = 0; ot < 6; ++ot) {
      bf16x8 a = *(const bf16x8*)&qkvw[(size_t)(w*96 + ot*16 + l15) * Dd + kt*32 + l4*8];
      #pragma unroll
      for (int mt = 0; mt < 4; ++mt) {
        acc[ot][mt] = __builtin_amdgcn_mfma_f32_16x16x32_bf16(a, bmh[mt], acc[ot][mt], 0, 0, 0);
        acc[ot][mt] = __builtin_amdgcn_mfma_f32_16x16x32_bf16(a, bml[mt], acc[ot][mt], 0, 0, 0);
      }
    }
  }

  #pragma unroll
  for (int ot = 0; ot < 6; ++ot) {
    const int ob = w*96 + ot*16;
    const int sel = ob >> 7;
    const int hz = (ob & 127) >> 4;
    #pragma unroll
    for (int mt = 0; mt < 4; ++mt) {
      int t = t0 + mt*16 + l15;
      int b = t / Nn, n = t - b * Nn;
      size_t bhn = (size_t)(b*Hh + hz) * Nn + n;
      f32x4 a = acc[ot][mt];
      if (sel == 0) {
        uint2 p;
        p.x = pack2bf(a[0]*0.36067376f, a[1]*0.36067376f);  // 0.25*log2(e)
        p.y = pack2bf(a[2]*0.36067376f, a[3]*0.36067376f);
        *(uint2*)&q[bhn*32 + l4*4] = p;
        uint2 z; z.x = 0u; z.y = 0u;
        *(uint2*)&q[bhn*32 + 16 + l4*4] = z;
      } else if (sel == 1) {
        uint2 p;
        p.x = pack2bf(a[0], a[1]);
        p.y = pack2bf(a[2], a[3]);
        *(uint2*)&k[bhn*32 + l4*4] = p;
        uint2 z; z.x = 0u; z.y = 0u;
        *(uint2*)&k[bhn*32 + 16 + l4*4] = z;
      } else {
        uint2 p;
        p.x = pack2bf(a[0], a[1]);
        p.y = pack2bf(a[2], a[3]);
        *(uint2*)&v[bhn*16 + l4*4] = p;
      }
    }
  }
}

// ---------------- K2: attention via MFMA (f32 out) ----------------
// grid 1280 (= 256 bh x 5 q-groups), block 320 (5 waves; 1 q-tile of 16 rows per wave).
__global__ __launch_bounds__(320) void attn_kernel(const short* __restrict__ q,
    const short* __restrict__ k, const short* __restrict__ v, float* __restrict__ attn)
{
  __shared__ short K_lds[400 * 32];
  __shared__ short VT[16 * KPAD];
  __shared__ short P[5][16 * PPAD];
  const int tid = threadIdx.x;
  const int bh = blockIdx.x / 5;
  const int qb = blockIdx.x % 5;

  {
    const uint4* kg = (const uint4*)(k + (size_t)bh * 400 * 32);
    uint4* kl = (uint4*)K_lds;
    #pragma unroll
    for (int it = 0; it < 5; ++it) kl[it*320 + tid] = kg[it*320 + tid];
  }
  {
    const unsigned* vg = (const unsigned*)(v + (size_t)bh * 400 * 16);
    #pragma unroll
    for (int it = 0; it < 10; ++it) {
      int lin = it*320 + tid;
      int key = lin >> 3, dp = lin & 7;
      unsigned pv = vg[key*8 + dp];
      VT[(2*dp)  * KPAD + key] = (short)(pv & 0xffffu);
      VT[(2*dp+1)* KPAD + key] = (short)(pv >> 16);
    }
    if (tid < 256) {
      int d = tid >> 4, key = 400 + (tid & 15);
      VT[d*KPAD + key] = 0;
    }
  }
  __syncthreads();

  const int w = tid >> 6, lane = tid & 63;
  const int l15 = lane & 15, g = lane >> 4;
  const int q0 = (qb*5 + w) * 16;

  const bf16x8 qf = *(const bf16x8*)&q[((size_t)bh*400 + q0 + l15)*32 + 8*g];
  short* Pw = &P[w][0];

  f32x4 zero4 = {0.f, 0.f, 0.f, 0.f};
  f32x4 o = zero4;
  float lsum = 0.f;

  for (int cc = 0; cc < 4; ++cc) {
    const int ntl = (cc < 3) ? 8 : 1;
    for (int t = 0; t < ntl; ++t) {
      int kt = cc*8 + t;
      bf16x8 kf = *(const bf16x8*)&K_lds[(kt*16 + l15)*32 + 8*g];
      f32x4 s = __builtin_amdgcn_mfma_f32_16x16x32_bf16(kf, qf, zero4, 0, 0, 0);
      float p0 = EXP2(s[0]);
      float p1 = EXP2(s[1]);
      float p2 = EXP2(s[2]);
      float p3 = EXP2(s[3]);
      lsum += (p0 + p1) + (p2 + p3);
      uint2 pk;
      pk.x = pack2bf(p0, p1);
      pk.y = pack2bf(p2, p3);
      *(uint2*)&Pw[l15*PPAD + t*16 + 4*g] = pk;
    }
    if (cc == 3) {
      uint2 z; z.x = 0u; z.y = 0u;
      *(uint2*)&Pw[l15*PPAD + 16 + 4*g] = z;
    }
    const int nm = (cc < 3) ? 4 : 1;
    for (int m = 0; m < nm; ++m) {
      bf16x8 vf = *(const bf16x8*)&VT[l15*KPAD + cc*128 + m*32 + 8*g];
      bf16x8 pf = *(const bf16x8*)&Pw[l15*PPAD + m*32 + 8*g];
      o = __builtin_amdgcn_mfma_f32_16x16x32_bf16(vf, pf, o, 0, 0, 0);
    }
  }

  lsum += __shfl_xor(lsum, 16, 64);
  lsum += __shfl_xor(lsum, 32, 64);
  float inv = 1.f / lsum;

  const int b = bh >> 3, h = bh & 7;
  float4 ov;
  ov.x = o[0]*inv; ov.y = o[1]*inv; ov.z = o[2]*inv; ov.w = o[3]*inv;
  *(float4*)&attn[((size_t)b*Nn + q0 + l15)*Dd + h*16 + 4*g] = ov;
}

// ---------------- K3: output proj (MFMA) + residual + LN1 + gating, fused ----------------
// grid 200, block 256 (4 waves x 32 outdims; 64 tokens/block).
__global__ __launch_bounds__(256) void proj_ln1_gate_kernel(
    const float* __restrict__ x, const float* __restrict__ attn,
    const short* __restrict__ wo_t, const float* __restrict__ bo,
    const float* __restrict__ g1, const float* __restrict__ b1n,
    const float* __restrict__ w_gate,
    float* __restrict__ out1,
    int* __restrict__ cnt, float* __restrict__ imp, float* __restrict__ loadv,
    int* __restrict__ etok, float* __restrict__ egate)
{
  __shared__ short as_[64][136];
  __shared__ float reds[4][64];
  __shared__ float reds2[4][64];
  __shared__ float mv[64][2];
  __shared__ float lgs[64*8];
  __shared__ float wgs[128*8];
  __shared__ float s_imp[8], s_load[8];
  __shared__ int s_cnt[8], s_base[8];

  const int tid = threadIdx.x;
  const int t0 = blockIdx.x * 64;

  #pragma unroll
  for (int it = 0; it < 8; ++it) {
    int lin = it * 256 + tid;
    int r = lin >> 5;
    int c4 = (lin & 31) << 2;
    float4 av = *(const float4*)&attn[(size_t)(t0 + r) * Dd + c4];
    uint2 p;
    p.x = pack2bf(av.x, av.y);
    p.y = pack2bf(av.z, av.w);
    *(uint2*)&as_[r][c4] = p;
  }
  #pragma unroll
  for (int it = 0; it < 4; ++it) wgs[it*256 + tid] = w_gate[it*256 + tid];
  lgs[tid] = 0.f; lgs[tid + 256] = 0.f;
  if (tid < 8) { s_imp[tid] = 0.f; s_load[tid] = 0.f; s_cnt[tid] = 0; }
  __syncthreads();

  const int lane = tid & 63, w = tid >> 6;
  const int l15 = lane & 15, l4 = lane >> 4;

  f32x4 zero4 = {0.f, 0.f, 0.f, 0.f};
  f32x4 y[2][4];
  #pragma unroll
  for (int dt = 0; dt < 2; ++dt)
    #pragma unroll
    for (int mt = 0; mt < 4; ++mt) y[dt][mt] = zero4;

  #pragma unroll
  for (int kt = 0; kt < 4; ++kt) {
    bf16x8 a0 = *(const bf16x8*)&wo_t[(size_t)(w*32 + l15) * Dd + kt*32 + l4*8];
    bf16x8 a1 = *(const bf16x8*)&wo_t[(size_t)(w*32 + 16 + l15) * Dd + kt*32 + l4*8];
    bf16x8 bm[4];
    #pragma unroll
    for (int mt = 0; mt < 4; ++mt)
      bm[mt] = *(const bf16x8*)&as_[mt*16 + l15][kt*32 + l4*8];
    #pragma unroll
    for (int mt = 0; mt < 4; ++mt) {
      y[0][mt] = __builtin_amdgcn_mfma_f32_16x16x32_bf16(a0, bm[mt], y[0][mt], 0, 0, 0);
      y[1][mt] = __builtin_amdgcn_mfma_f32_16x16x32_bf16(a1, bm[mt], y[1][mt], 0, 0, 0);
    }
  }

  // r = proj + bo + x; accumulate per-token sum/sumsq partials
  float4 bov[2];
  bov[0] = *(const float4*)&bo[w*32 + 0*16 + l4*4];
  bov[1] = *(const float4*)&bo[w*32 + 1*16 + l4*4];
  float sP[4], s2P[4];
  #pragma unroll
  for (int mt = 0; mt < 4; ++mt) { sP[mt] = 0.f; s2P[mt] = 0.f; }
  #pragma unroll
  for (int mt = 0; mt < 4; ++mt) {
    int row = mt*16 + l15;
    #pragma unroll
    for (int dt = 0; dt < 2; ++dt) {
      int dim = w*32 + dt*16 + l4*4;
      float4 xv = *(const float4*)&x[(size_t)(t0 + row) * Dd + dim];
      float4 bv = bov[dt];
      f32x4 r = y[dt][mt];
      r[0] += bv.x + xv.x; r[1] += bv.y + xv.y;
      r[2] += bv.z + xv.z; r[3] += bv.w + xv.w;
      y[dt][mt] = r;
      sP[mt]  += (r[0] + r[1]) + (r[2] + r[3]);
      s2P[mt] += (r[0]*r[0] + r[1]*r[1]) + (r[2]*r[2] + r[3]*r[3]);
    }
  }
  #pragma unroll
  for (int mt = 0; mt < 4; ++mt) {
    sP[mt]  += __shfl_xor(sP[mt], 16, 64);  sP[mt]  += __shfl_xor(sP[mt], 32, 64);
    s2P[mt] += __shfl_xor(s2P[mt], 16, 64); s2P[mt] += __shfl_xor(s2P[mt], 32, 64);
  }
  if (l4 == 0) {
    #pragma unroll
    for (int mt = 0; mt < 4; ++mt) {
      reds[w][mt*16 + l15] = sP[mt];
      reds2[w][mt*16 + l15] = s2P[mt];
    }
  }
  __syncthreads();
  if (tid < 64) {
    float s = reds[0][tid] + reds[1][tid] + reds[2][tid] + reds[3][tid];
    float s2 = reds2[0][tid] + reds2[1][tid] + reds2[2][tid] + reds2[3][tid];
    float m = s * (1.f/128.f);
    float var = s2 * (1.f/128.f) - m*m;
    mv[tid][0] = m;
    mv[tid][1] = rsqrtf(var + 1e-5f);
  }
  __syncthreads();

  // LN output + out1 write + logit partials
  float4 gv[2], bv2[2];
  #pragma unroll
  for (int dt = 0; dt < 2; ++dt) {
    gv[dt]  = *(const float4*)&g1[w*32 + dt*16 + l4*4];
    bv2[dt] = *(const float4*)&b1n[w*32 + dt*16 + l4*4];
  }
  #pragma unroll
  for (int mt = 0; mt < 4; ++mt) {
    int row = mt*16 + l15;
    float m = mv[row][0], inv = mv[row][1];
    float lg[8];
    #pragma unroll
    for (int e = 0; e < 8; ++e) lg[e] = 0.f;
    #pragma unroll
    for (int dt = 0; dt < 2; ++dt) {
      int dim = w*32 + dt*16 + l4*4;
      f32x4 r = y[dt][mt];
      float o0 = (r[0]-m)*inv*((float*)&gv[dt])[0] + ((float*)&bv2[dt])[0];
      float o1 = (r[1]-m)*inv*((float*)&gv[dt])[1] + ((float*)&bv2[dt])[1];
      float o2 = (r[2]-m)*inv*((float*)&gv[dt])[2] + ((float*)&bv2[dt])[2];
      float o3 = (r[3]-m)*inv*((float*)&gv[dt])[3] + ((float*)&bv2[dt])[3];
      float4 ov; ov.x = o0; ov.y = o1; ov.z = o2; ov.w = o3;
      *(float4*)&out1[(size_t)(t0 + row) * Dd + dim] = ov;
      #pragma unroll
      for (int e = 0; e < 8; ++e)
        lg[e] += o0*wgs[(dim+0)*8+e] + o1*wgs[(dim+1)*8+e]
               + o2*wgs[(dim+2)*8+e] + o3*wgs[(dim+3)*8+e];
    }
    #pragma unroll
    for (int e = 0; e < 8; ++e) {
      lg[e] += __shfl_xor(lg[e], 16, 64);
      lg[e] += __shfl_xor(lg[e], 32, 64);
    }
    if (l4 == 0) {
      #pragma unroll
      for (int e = 0; e < 8; ++e) atomicAdd(&lgs[row*8 + e], lg[e]);
    }
  }
  __syncthreads();

  // top-2 gating per token (threads 0..63)
  int i0 = 0, i1 = -1, p0 = 0, p1 = 0;
  float g0 = 0.f, gg1 = 0.f;
  if (tid < 64) {
    float lgv[8];
    #pragma unroll
    for (int e = 0; e < 8; ++e) lgv[e] = lgs[tid*8 + e];
    float v0 = lgv[0];
    #pragma unroll
    for (int e = 1; e < 8; ++e) if (lgv[e] > v0) { v0 = lgv[e]; i0 = e; }
    float v1 = -INFINITY;
    #pragma unroll
    for (int e = 0; e < 8; ++e) if (e != i0 && lgv[e] > v1) { v1 = lgv[e]; i1 = e; }
    g0 = 1.f / (1.f + __expf(v1 - v0));
    gg1 = 1.f - g0;
    atomicAdd(&s_imp[i0], g0);  atomicAdd(&s_imp[i1], gg1);
    atomicAdd(&s_load[i0], 1.f); atomicAdd(&s_load[i1], 1.f);
    p0 = atomicAdd(&s_cnt[i0], 1);
    p1 = atomicAdd(&s_cnt[i1], 1);
  }
  __syncthreads();
  if (tid < 8) {
    s_base[tid] = atomicAdd(&cnt[tid], s_cnt[tid]);
    atomicAdd(&imp[tid], s_imp[tid]);
    atomicAdd(&loadv[tid], s_load[tid]);
  }
  __syncthreads();
  if (tid < 64) {
    int t = t0 + tid;
    int o0 = i0 * Tt + s_base[i0] + p0;
    etok[o0] = t;               egate[o0] = g0;
    int o1 = i1 * Tt + s_base[i1] + p1;
    etok[o1] = t | (1 << 30);   egate[o1] = gg1;
  }
}

// ---------------- K6: grouped sparse MoE FFN (MFMA bf16) ----------------
__global__ __launch_bounds__(256) void moe_kernel(const float* __restrict__ out1,
    const short* __restrict__ W1t, const float* __restrict__ b1,
    const short* __restrict__ W2t, const float* __restrict__ b2,
    const int* __restrict__ cnt, const int* __restrict__ etok, const float* __restrict__ egate,
    float* __restrict__ moe0, float* __restrict__ moe1)
{
  __shared__ short xs[64][136];
  __shared__ short hs[64][136];
  __shared__ int els[64];
  __shared__ float gls[64];

  const int e = blockIdx.y;
  const int count = cnt[e];
  const int t0 = blockIdx.x * 64;
  if (t0 >= count) return;
  const int nt = min(64, count - t0);
  const int tid = threadIdx.x;

  if (tid < 64) {
    int idx = (tid < nt) ? tid : 0;
    els[tid] = etok[e * Tt + t0 + idx];
    gls[tid] = (tid < nt) ? egate[e * Tt + t0 + tid] : 0.f;
  }
  __syncthreads();

  #pragma unroll
  for (int it = 0; it < 8; ++it) {
    int lin = it * 256 + tid;
    int r = lin >> 5;
    int c4 = (lin & 31) << 2;
    int tok = els[r] & 0x3FFFFFFF;
    float4 xv = *(const float4*)&out1[(size_t)tok * Dd + c4];
    uint2 p;
    p.x = pack2bf(xv.x, xv.y);
    p.y = pack2bf(xv.z, xv.w);
    *(uint2*)&xs[r][c4] = p;
  }
  __syncthreads();

  const int lane = tid & 63;
  const int w = tid >> 6;
  const int l15 = lane & 15;
  const int l4 = lane >> 4;

  f32x4 zero4 = {0.f, 0.f, 0.f, 0.f};
  f32x4 y[2][4];
  #pragma unroll
  for (int dt = 0; dt < 2; ++dt)
    #pragma unroll
    for (int mt = 0; mt < 4; ++mt) y[dt][mt] = zero4;

  const short* W1p = W1t + (size_t)e * FFd * Dd;
  const short* W2p = W2t + (size_t)e * Dd * FFd;

  for (int ch = 0; ch < 4; ++ch) {
    f32x4 h[2][4];
    #pragma unroll
    for (int ft = 0; ft < 2; ++ft)
      #pragma unroll
      for (int mt = 0; mt < 4; ++mt) h[ft][mt] = zero4;

    #pragma unroll
    for (int kt = 0; kt < 4; ++kt) {
      bf16x8 a0 = *(const bf16x8*)&W1p[(size_t)(ch*128 + w*32 + 0*16 + l15) * Dd + kt*32 + l4*8];
      bf16x8 a1 = *(const bf16x8*)&W1p[(size_t)(ch*128 + w*32 + 1*16 + l15) * Dd + kt*32 + l4*8];
      bf16x8 bm[4];
      #pragma unroll
      for (int mt = 0; mt < 4; ++mt)
        bm[mt] = *(const bf16x8*)&xs[mt*16 + l15][kt*32 + l4*8];
      #pragma unroll
      for (int mt = 0; mt < 4; ++mt) {
        h[0][mt] = __builtin_amdgcn_mfma_f32_16x16x32_bf16(a0, bm[mt], h[0][mt], 0, 0, 0);
        h[1][mt] = __builtin_amdgcn_mfma_f32_16x16x32_bf16(a1, bm[mt], h[1][mt], 0, 0, 0);
      }
    }

    float4 b1v0 = *(const float4*)&b1[e*FFd + ch*128 + w*32 + 0*16 + l4*4];
    float4 b1v1 = *(const float4*)&b1[e*FFd + ch*128 + w*32 + 1*16 + l4*4];
    __syncthreads();
    #pragma unroll
    for (int mt = 0; mt < 4; ++mt) {
      uint2 p0, p1;
      p0.x = pack2bf(fmaxf(h[0][mt][0] + b1v0.x, 0.f), fmaxf(h[0][mt][1] + b1v0.y, 0.f));
      p0.y = pack2bf(fmaxf(h[0][mt][2] + b1v0.z, 0.f), fmaxf(h[0][mt][3] + b1v0.w, 0.f));
      *(uint2*)&hs[mt*16 + l15][w*32 + 0*16 + l4*4] = p0;
      p1.x = pack2bf(fmaxf(h[1][mt][0] + b1v1.x, 0.f), fmaxf(h[1][mt][1] + b1v1.y, 0.f));
      p1.y = pack2bf(fmaxf(h[1][mt][2] + b1v1.z, 0.f), fmaxf(h[1][mt][3] + b1v1.w, 0.f));
      *(uint2*)&hs[mt*16 + l15][w*32 + 1*16 + l4*4] = p1;
    }
    __syncthreads();

    #pragma unroll
    for (int kt = 0; kt < 4; ++kt) {
      bf16x8 a0 = *(const bf16x8*)&W2p[(size_t)(w*32 + 0*16 + l15) * FFd + ch*128 + kt*32 + l4*8];
      bf16x8 a1 = *(const bf16x8*)&W2p[(size_t)(w*32 + 1*16 + l15) * FFd + ch*128 + kt*32 + l4*8];
      bf16x8 bm[4];
      #pragma unroll
      for (int mt = 0; mt < 4; ++mt)
        bm[mt] = *(const bf16x8*)&hs[mt*16 + l15][kt*32 + l4*8];
      #pragma unroll
      for (int mt = 0; mt < 4; ++mt) {
        y[0][mt] = __builtin_amdgcn_mfma_f32_16x16x32_bf16(a0, bm[mt], y[0][mt], 0, 0, 0);
        y[1][mt] = __builtin_amdgcn_mfma_f32_16x16x32_bf16(a1, bm[mt], y[1][mt], 0, 0, 0);
      }
    }
  }

  float4 b2v[2];
  b2v[0] = *(const float4*)&b2[e*Dd + w*32 + 0*16 + l4*4];
  b2v[1] = *(const float4*)&b2[e*Dd + w*32 + 1*16 + l4*4];
  #pragma unroll
  for (int mt = 0; mt < 4; ++mt) {
    int m = mt*16 + l15;
    if (m < nt) {
      int raw = els[m];
      int t = raw & 0x3FFFFFFF;
      float g = gls[m];
      float* basep = (raw & (1 << 30)) ? moe1 : moe0;
      #pragma unroll
      for (int dt = 0; dt < 2; ++dt) {
        float4 v;
        v.x = g * (y[dt][mt][0] + ((dt == 0) ? b2v[0].x : b2v[1].x));
        v.y = g * (y[dt][mt][1] + ((dt == 0) ? b2v[0].y : b2v[1].y));
        v.z = g * (y[dt][mt][2] + ((dt == 0) ? b2v[0].z : b2v[1].z));
        v.w = g * (y[dt][mt][3] + ((dt == 0) ? b2v[0].w : b2v[1].w));
        *(float4*)&basep[(size_t)t * Dd + w*32 + dt*16 + l4*4] = v;
      }
    }
  }
}

// ---------------- K7: residual + LN2 -> d_out (+ loss in block 0) ----------------
__global__ __launch_bounds__(256) void ln2_kernel(const float* __restrict__ out1,
    const float* __restrict__ moe0, const float* __restrict__ moe1,
    const float* __restrict__ g, const float* __restrict__ bb,
    const float* __restrict__ imp, const float* __restrict__ loadv,
    float* __restrict__ out, float* __restrict__ out_loss)
{
  __shared__ float red[8];
  const int tid = threadIdx.x;
  const int half = tid >> 7;
  const int j = tid & 127;
  const int t = blockIdx.x * 2 + half;
  float r = out1[t * Dd + j] + moe0[t * Dd + j] + moe1[t * Dd + j];

  float s = r;
  #pragma unroll
  for (int off = 32; off > 0; off >>= 1) s += __shfl_xor(s, off, 64);
  const int wid = tid >> 6;
  if ((tid & 63) == 0) red[wid] = s;
  __syncthreads();
  float mean = (red[half*2] + red[half*2+1]) * (1.f/128.f);
  float dv = r - mean;
  float s2 = dv * dv;
  #pragma unroll
  for (int off = 32; off > 0; off >>= 1) s2 += __shfl_xor(s2, off, 64);
  if ((tid & 63) == 0) red[4 + wid] = s2;
  __syncthreads();
  float var = (red[4 + half*2] + red[4 + half*2+1]) * (1.f/128.f);
  out[t * Dd + j] = dv * rsqrtf(var + 1e-5f) * g[j] + bb[j];

  if (blockIdx.x == 0 && tid == 0) {
    float m1 = 0.f;
    for (int e = 0; e < 8; ++e) m1 += imp[e];
    m1 *= 0.125f;
    float v1 = 0.f;
    for (int e = 0; e < 8; ++e) { float d = imp[e] - m1; v1 += d * d; }
    v1 *= 0.125f;
    float c1 = v1 / (m1 * m1 + 1e-10f);
    float m2 = 0.f;
    for (int e = 0; e < 8; ++e) m2 += loadv[e];
    m2 *= 0.125f;
    float v2 = 0.f;
    for (int e = 0; e < 8; ++e) { float d = loadv[e] - m2; v2 += d * d; }
    v2 *= 0.125f;
    float c2 = v2 / (m2 * m2 + 1e-10f);
    out_loss[0] = (c1 + c2) * 0.01f;
  }
}

extern "C" void kernel_launch(void* const* d_in, const int* in_sizes, int n_in,
                              void* d_out, int out_size, void* d_ws, size_t ws_size,
                              hipStream_t stream)
{
  (void)in_sizes; (void)n_in; (void)out_size; (void)ws_size;
  const float* x      = (const float*)d_in[0];
  const float* Wq     = (const float*)d_in[1];
  const float* Wk     = (const float*)d_in[2];
  const float* Wv     = (const float*)d_in[3];
  const float* Wo     = (const float*)d_in[4];
  const float* bo     = (const float*)d_in[5];
  const float* ln1_g  = (const float*)d_in[6];
  const float* ln1_b  = (const float*)d_in[7];
  const float* w_gate = (const float*)d_in[8];
  const float* W1     = (const float*)d_in[9];
  const float* b1     = (const float*)d_in[10];
  const float* W2     = (const float*)d_in[11];
  const float* b2     = (const float*)d_in[12];
  const float* ln2_g  = (const float*)d_in[13];
  const float* ln2_b  = (const float*)d_in[14];

  // CORRECT sizes: q/k are [BH][400][32] bf16 = 256*400*32*2 = 6,553,600 B each;
  // v is [BH][400][16] bf16 = 3,276,800 B.  (R4/R5 bug: sized these 8x too small.)
  char* wsb = (char*)d_ws;
  size_t off = 0;
  float* attn    = (float*)(wsb + off); off += (size_t)Tt*Dd*4;          //  6,553,600 (reused: moe0)
  float* out1    = (float*)(wsb + off); off += (size_t)Tt*Dd*4;          //  6,553,600
  short* q_bf    = (short*)(wsb + off); off += (size_t)Tt*Hh*32*2;       //  6,553,600 (reused: etok+egate)
  short* k_bf    = (short*)(wsb + off); off += (size_t)Tt*Hh*32*2;       //  6,553,600 (reused: moe1)
  short* v_bf    = (short*)(wsb + off); off += (size_t)Tt*Hh*16*2;       //  3,276,800
  short* W1t     = (short*)(wsb + off); off += (size_t)Ee*FFd*Dd*2;      //  1,048,576
  short* W2t     = (short*)(wsb + off); off += (size_t)Ee*FFd*Dd*2;      //  1,048,576
  short* wo_t    = (short*)(wsb + off); off += (size_t)Dd*Dd*2;          //     32,768
  short* qkvw    = (short*)(wsb + off); off += (size_t)384*Dd*2;         //     98,304
  int*   gmeta   = (int*)(wsb + off);   off += 256;                      // total 31,719,680 B

  float* moe0  = attn;
  float* moe1  = (float*)k_bf;                 // free after attn (6.5 MB)
  int*   cnt   = gmeta;
  float* imp   = (float*)(gmeta + 8);
  float* loadv = (float*)(gmeta + 16);
  int*   etok  = (int*)q_bf;                   // 409,600 B, free after attn
  float* egate = (float*)((char*)q_bf + (size_t)Ee*Tt*4);   // next 409,600 B

  float* out3 = (float*)d_out;
  float* loss = out3 + Tt * Dd;

  prep_kernel<<<1088, 256, 0, stream>>>(W1, W2, Wo, Wq, Wk, Wv, W1t, W2t, wo_t, qkvw, gmeta);
  qkv_kernel<<<200, 256, 0, stream>>>(x, qkvw, q_bf, k_bf, v_bf);
  attn_kernel<<<1280, 320, 0, stream>>>(q_bf, k_bf, v_bf, attn);
  proj_ln1_gate_kernel<<<200, 256, 0, stream>>>(x, attn, wo_t, bo, ln1_g, ln1_b, w_gate,
                                                out1, cnt, imp, loadv, etok, egate);
  moe_kernel<<<dim3(200, 8), 256, 0, stream>>>(out1, W1t, b1, W2t, b2, cnt, etok, egate, moe0, moe1);
  ln2_kernel<<<Tt/2, 256, 0, stream>>>(out1, moe0, moe1, ln2_g, ln2_b, imp, loadv, out3, loss);
}

// Round 7
// 102.221 us; speedup vs baseline: 3.1450x; 1.0551x over previous
//
#include <hip/hip_runtime.h>
#include <math.h>

#define Bb 32
#define Nn 400
#define Dd 128
#define Hh 8
#define QKd 16
#define FFd 512
#define Ee 8
#define Tt (Bb*Nn)   // 12800
#define KPAD 424     // VT row stride (bf16 elems)
#define PP2 34       // P row stride (bf16 elems)

typedef __attribute__((ext_vector_type(8))) __bf16 bf16x8;
typedef __attribute__((ext_vector_type(4))) float f32x4;

#if defined(__has_builtin)
#if __has_builtin(__builtin_amdgcn_exp2f)
#define EXP2(x) __builtin_amdgcn_exp2f(x)
#endif
#endif
#ifndef EXP2
#define EXP2(x) __expf((x) * 0.69314718f)
#endif

__device__ __forceinline__ short f2bf(float f){
  union { float f; unsigned u; } v; v.f = f;
  unsigned r = v.u + 0x7FFFu + ((v.u >> 16) & 1u);
  return (short)(r >> 16);
}
__device__ __forceinline__ unsigned pack2bf(float a, float b){
  return (unsigned)(unsigned short)f2bf(a) | ((unsigned)(unsigned short)f2bf(b) << 16);
}
__device__ __forceinline__ bf16x8 zero_bf16x8(){
  union { uint4 u; bf16x8 b; } z;
  z.u.x = 0u; z.u.y = 0u; z.u.z = 0u; z.u.w = 0u;
  return z.b;
}

// ---------------- K0: prep — all weight transposes (f32 -> bf16^T) + zero gate meta ----------------
__global__ __launch_bounds__(256) void prep_kernel(
    const float* __restrict__ W1, const float* __restrict__ W2, const float* __restrict__ Wo,
    const float* __restrict__ Wq, const float* __restrict__ Wk, const float* __restrict__ Wv,
    short* __restrict__ W1t, short* __restrict__ W2t, short* __restrict__ wo_t,
    short* __restrict__ qkvw, int* __restrict__ gmeta)
{
  const int bid = blockIdx.x;
  if (bid == 0 && threadIdx.x < 24) gmeta[threadIdx.x] = 0;   // cnt[8], imp[8], loadv[8]

  const float* in; short* out; int C, tile;
  if (bid < 512)        { int e = bid >> 6;         tile = bid & 63;          in = W1 + e*65536; out = W1t + e*65536; C = 512; }
  else if (bid < 1024)  { int e = (bid - 512) >> 6; tile = (bid - 512) & 63;  in = W2 + e*65536; out = W2t + e*65536; C = 128; }
  else if (bid < 1040)  { tile = bid - 1024; in = Wo; out = wo_t;          C = 128; }
  else if (bid < 1056)  { tile = bid - 1040; in = Wq; out = qkvw;          C = 128; }
  else if (bid < 1072)  { tile = bid - 1056; in = Wk; out = qkvw + 16384;  C = 128; }
  else                  { tile = bid - 1072; in = Wv; out = qkvw + 32768;  C = 128; }
  const int R = (bid < 512) ? 128 : (bid < 1024 ? 512 : 128);

  __shared__ float t32[32][33];
  const int nCt = C >> 5;
  const int c0 = (tile % nCt) << 5;
  const int r0 = (tile / nCt) << 5;
  const int tx = threadIdx.x & 31, ty = threadIdx.x >> 5;
  #pragma unroll
  for (int i = 0; i < 4; ++i)
    t32[ty + 8*i][tx] = in[(size_t)(r0 + ty + 8*i) * C + c0 + tx];
  __syncthreads();
  #pragma unroll
  for (int i = 0; i < 4; ++i)
    out[(size_t)(c0 + ty + 8*i) * R + r0 + tx] = f2bf(t32[tx][ty + 8*i]);
}

// ---------------- K1: QKV projection via MFMA, split-bf16 activations ----------------
// grid 200, block 256. qkvw: [384][128] bf16. Outputs q,k,v all [BH][400][16] bf16 (q pre-scaled).
__global__ __launch_bounds__(256) void qkv_kernel(const float* __restrict__ x,
    const short* __restrict__ qkvw,
    short* __restrict__ q, short* __restrict__ k, short* __restrict__ v)
{
  __shared__ short xsh[64][136];
  __shared__ short xsl[64][136];
  const int tid = threadIdx.x;
  const int t0 = blockIdx.x * 64;

  #pragma unroll
  for (int it = 0; it < 8; ++it) {
    int lin = it * 256 + tid;
    int r = lin >> 5;
    int c4 = (lin & 31) << 2;
    float4 xv = *(const float4*)&x[(size_t)(t0 + r) * Dd + c4];
    unsigned h01 = pack2bf(xv.x, xv.y);
    unsigned h23 = pack2bf(xv.z, xv.w);
    union { unsigned u; float f; } ua, ub, uc, ud;
    ua.u = h01 << 16; ub.u = h01 & 0xFFFF0000u;
    uc.u = h23 << 16; ud.u = h23 & 0xFFFF0000u;
    unsigned l01 = pack2bf(xv.x - ua.f, xv.y - ub.f);
    unsigned l23 = pack2bf(xv.z - uc.f, xv.w - ud.f);
    uint2 ph; ph.x = h01; ph.y = h23;
    uint2 pl; pl.x = l01; pl.y = l23;
    *(uint2*)&xsh[r][c4] = ph;
    *(uint2*)&xsl[r][c4] = pl;
  }
  __syncthreads();

  const int lane = tid & 63, w = tid >> 6;
  const int l15 = lane & 15, l4 = lane >> 4;

  f32x4 zero4 = {0.f, 0.f, 0.f, 0.f};
  f32x4 acc[6][4];
  #pragma unroll
  for (int ot = 0; ot < 6; ++ot)
    #pragma unroll
    for (int mt = 0; mt < 4; ++mt) acc[ot][mt] = zero4;

  #pragma unroll
  for (int kt = 0; kt < 4; ++kt) {
    bf16x8 bmh[4], bml[4];
    #pragma unroll
    for (int mt = 0; mt < 4; ++mt) {
      bmh[mt] = *(const bf16x8*)&xsh[mt*16 + l15][kt*32 + l4*8];
      bml[mt] = *(const bf16x8*)&xsl[mt*16 + l15][kt*32 + l4*8];
    }
    #pragma unroll
    for (int ot = 0; ot < 6; ++ot) {
      bf16x8 a = *(const bf16x8*)&qkvw[(size_t)(w*96 + ot*16 + l15) * Dd + kt*32 + l4*8];
      #pragma unroll
      for (int mt = 0; mt < 4; ++mt) {
        acc[ot][mt] = __builtin_amdgcn_mfma_f32_16x16x32_bf16(a, bmh[mt], acc[ot][mt], 0, 0, 0);
        acc[ot][mt] = __builtin_amdgcn_mfma_f32_16x16x32_bf16(a, bml[mt], acc[ot][mt], 0, 0, 0);
      }
    }
  }

  #pragma unroll
  for (int ot = 0; ot < 6; ++ot) {
    const int ob = w*96 + ot*16;
    const int sel = ob >> 7;
    const int hz = (ob & 127) >> 4;
    #pragma unroll
    for (int mt = 0; mt < 4; ++mt) {
      int t = t0 + mt*16 + l15;
      int b = t / Nn, n = t - b * Nn;
      size_t bhn = (size_t)(b*Hh + hz) * Nn + n;
      f32x4 a = acc[ot][mt];
      uint2 p;
      if (sel == 0) {
        p.x = pack2bf(a[0]*0.36067376f, a[1]*0.36067376f);  // 0.25*log2(e)
        p.y = pack2bf(a[2]*0.36067376f, a[3]*0.36067376f);
        *(uint2*)&q[bhn*16 + l4*4] = p;
      } else if (sel == 1) {
        p.x = pack2bf(a[0], a[1]);
        p.y = pack2bf(a[2], a[3]);
        *(uint2*)&k[bhn*16 + l4*4] = p;
      } else {
        p.x = pack2bf(a[0], a[1]);
        p.y = pack2bf(a[2], a[3]);
        *(uint2*)&v[bhn*16 + l4*4] = p;
      }
    }
  }
}

// ---------------- K2: attention via MFMA, one block per bh ----------------
// grid 256, block 512 (8 waves). Wave w owns q-tiles {w, w+8, w+16, w+24} (<25).
// K fragments loaded directly from global (coalesced); VT staged once; P per-wave scratch.
__global__ __launch_bounds__(512) void attn_kernel(const short* __restrict__ q,
    const short* __restrict__ k, const short* __restrict__ v, float* __restrict__ attn)
{
  __shared__ short VT[16 * KPAD];        // 13568 B
  __shared__ short P[8][4][16 * PP2];    // 34816 B
  const int tid = threadIdx.x;
  const int bh = blockIdx.x;

  // stage V^T once
  {
    const unsigned* vg = (const unsigned*)(v + (size_t)bh * 400 * 16);
    #pragma unroll
    for (int it = 0; it < 7; ++it) {
      int lin = it*512 + tid;
      if (lin < 3200) {
        int key = lin >> 3, dp = lin & 7;
        unsigned pv = vg[key*8 + dp];
        VT[(2*dp)  * KPAD + key] = (short)(pv & 0xffffu);
        VT[(2*dp+1)* KPAD + key] = (short)(pv >> 16);
      }
    }
    if (tid < 256) {   // zero pad keys 400..415
      int d = tid >> 4, key = 400 + (tid & 15);
      VT[d*KPAD + key] = 0;
    }
  }
  __syncthreads();

  const int w = tid >> 6, lane = tid & 63;
  const int l15 = lane & 15, g = lane >> 4;

  f32x4 zero4 = {0.f, 0.f, 0.f, 0.f};
  f32x4 o[4];
  float lsum[4];
  bf16x8 qf[4];
  #pragma unroll
  for (int i = 0; i < 4; ++i) {
    o[i] = zero4; lsum[i] = 0.f;
    int qt = w + 8*i;
    if (qt < 25 && g < 2)
      qf[i] = *(const bf16x8*)&q[((size_t)bh*400 + qt*16 + l15)*16 + 8*g];
    else
      qf[i] = zero_bf16x8();
  }

  #pragma unroll
  for (int cc = 0; cc < 13; ++cc) {
    #pragma unroll
    for (int sub = 0; sub < 2; ++sub) {
      const int kt = cc*2 + sub;
      if (kt < 25) {
        bf16x8 kf;
        if (g < 2) kf = *(const bf16x8*)&k[((size_t)bh*400 + kt*16 + l15)*16 + 8*g];
        else       kf = zero_bf16x8();
        #pragma unroll
        for (int i = 0; i < 4; ++i) {
          int qt = w + 8*i;
          if (qt < 25) {
            f32x4 s = __builtin_amdgcn_mfma_f32_16x16x32_bf16(kf, qf[i], zero4, 0, 0, 0);
            float p0 = EXP2(s[0]);
            float p1 = EXP2(s[1]);
            float p2 = EXP2(s[2]);
            float p3 = EXP2(s[3]);
            lsum[i] += (p0 + p1) + (p2 + p3);
            uint2 pk;
            pk.x = pack2bf(p0, p1);
            pk.y = pack2bf(p2, p3);
            *(uint2*)&P[w][i][l15*PP2 + sub*16 + 4*g] = pk;
          }
        }
      } else {   // kt == 25: keys 400..415 -> P = 0
        uint2 z; z.x = 0u; z.y = 0u;
        #pragma unroll
        for (int i = 0; i < 4; ++i) {
          int qt = w + 8*i;
          if (qt < 25) *(uint2*)&P[w][i][l15*PP2 + sub*16 + 4*g] = z;
        }
      }
    }
    // PV for this 32-key chunk (same-wave LDS, no barrier needed)
    bf16x8 vf = *(const bf16x8*)&VT[l15*KPAD + cc*32 + 8*g];
    #pragma unroll
    for (int i = 0; i < 4; ++i) {
      int qt = w + 8*i;
      if (qt < 25) {
        bf16x8 pf = *(const bf16x8*)&P[w][i][l15*PP2 + 8*g];
        o[i] = __builtin_amdgcn_mfma_f32_16x16x32_bf16(vf, pf, o[i], 0, 0, 0);
      }
    }
  }

  const int b = bh >> 3, h = bh & 7;
  #pragma unroll
  for (int i = 0; i < 4; ++i) {
    int qt = w + 8*i;
    if (qt < 25) {
      float ls = lsum[i];
      ls += __shfl_xor(ls, 16, 64);
      ls += __shfl_xor(ls, 32, 64);
      float inv = 1.f / ls;
      float4 ov;
      ov.x = o[i][0]*inv; ov.y = o[i][1]*inv; ov.z = o[i][2]*inv; ov.w = o[i][3]*inv;
      *(float4*)&attn[((size_t)b*Nn + qt*16 + l15)*Dd + h*16 + 4*g] = ov;
    }
  }
}

// ---------------- K3: output proj (MFMA) + residual + LN1 + gating, fused ----------------
// grid 200, block 256 (4 waves x 32 outdims; 64 tokens/block).
__global__ __launch_bounds__(256) void proj_ln1_gate_kernel(
    const float* __restrict__ x, const float* __restrict__ attn,
    const short* __restrict__ wo_t, const float* __restrict__ bo,
    const float* __restrict__ g1, const float* __restrict__ b1n,
    const float* __restrict__ w_gate,
    float* __restrict__ out1, short* __restrict__ out1b,
    int* __restrict__ cnt, float* __restrict__ imp, float* __restrict__ loadv,
    int* __restrict__ etok, float* __restrict__ egate)
{
  __shared__ short as_[64][136];
  __shared__ float reds[4][64];
  __shared__ float reds2[4][64];
  __shared__ float mv[64][2];
  __shared__ float lgs[64*8];
  __shared__ float wgs[128*8];
  __shared__ float s_imp[8], s_load[8];
  __shared__ int s_cnt[8], s_base[8];

  const int tid = threadIdx.x;
  const int t0 = blockIdx.x * 64;

  #pragma unroll
  for (int it = 0; it < 8; ++it) {
    int lin = it * 256 + tid;
    int r = lin >> 5;
    int c4 = (lin & 31) << 2;
    float4 av = *(const float4*)&attn[(size_t)(t0 + r) * Dd + c4];
    uint2 p;
    p.x = pack2bf(av.x, av.y);
    p.y = pack2bf(av.z, av.w);
    *(uint2*)&as_[r][c4] = p;
  }
  #pragma unroll
  for (int it = 0; it < 4; ++it) wgs[it*256 + tid] = w_gate[it*256 + tid];
  lgs[tid] = 0.f; lgs[tid + 256] = 0.f;
  if (tid < 8) { s_imp[tid] = 0.f; s_load[tid] = 0.f; s_cnt[tid] = 0; }
  __syncthreads();

  const int lane = tid & 63, w = tid >> 6;
  const int l15 = lane & 15, l4 = lane >> 4;

  f32x4 zero4 = {0.f, 0.f, 0.f, 0.f};
  f32x4 y[2][4];
  #pragma unroll
  for (int dt = 0; dt < 2; ++dt)
    #pragma unroll
    for (int mt = 0; mt < 4; ++mt) y[dt][mt] = zero4;

  #pragma unroll
  for (int kt = 0; kt < 4; ++kt) {
    bf16x8 a0 = *(const bf16x8*)&wo_t[(size_t)(w*32 + l15) * Dd + kt*32 + l4*8];
    bf16x8 a1 = *(const bf16x8*)&wo_t[(size_t)(w*32 + 16 + l15) * Dd + kt*32 + l4*8];
    bf16x8 bm[4];
    #pragma unroll
    for (int mt = 0; mt < 4; ++mt)
      bm[mt] = *(const bf16x8*)&as_[mt*16 + l15][kt*32 + l4*8];
    #pragma unroll
    for (int mt = 0; mt < 4; ++mt) {
      y[0][mt] = __builtin_amdgcn_mfma_f32_16x16x32_bf16(a0, bm[mt], y[0][mt], 0, 0, 0);
      y[1][mt] = __builtin_amdgcn_mfma_f32_16x16x32_bf16(a1, bm[mt], y[1][mt], 0, 0, 0);
    }
  }

  float4 bov[2];
  bov[0] = *(const float4*)&bo[w*32 + 0*16 + l4*4];
  bov[1] = *(const float4*)&bo[w*32 + 1*16 + l4*4];
  float sP[4], s2P[4];
  #pragma unroll
  for (int mt = 0; mt < 4; ++mt) { sP[mt] = 0.f; s2P[mt] = 0.f; }
  #pragma unroll
  for (int mt = 0; mt < 4; ++mt) {
    int row = mt*16 + l15;
    #pragma unroll
    for (int dt = 0; dt < 2; ++dt) {
      int dim = w*32 + dt*16 + l4*4;
      float4 xv = *(const float4*)&x[(size_t)(t0 + row) * Dd + dim];
      float4 bv = bov[dt];
      f32x4 r = y[dt][mt];
      r[0] += bv.x + xv.x; r[1] += bv.y + xv.y;
      r[2] += bv.z + xv.z; r[3] += bv.w + xv.w;
      y[dt][mt] = r;
      sP[mt]  += (r[0] + r[1]) + (r[2] + r[3]);
      s2P[mt] += (r[0]*r[0] + r[1]*r[1]) + (r[2]*r[2] + r[3]*r[3]);
    }
  }
  #pragma unroll
  for (int mt = 0; mt < 4; ++mt) {
    sP[mt]  += __shfl_xor(sP[mt], 16, 64);  sP[mt]  += __shfl_xor(sP[mt], 32, 64);
    s2P[mt] += __shfl_xor(s2P[mt], 16, 64); s2P[mt] += __shfl_xor(s2P[mt], 32, 64);
  }
  if (l4 == 0) {
    #pragma unroll
    for (int mt = 0; mt < 4; ++mt) {
      reds[w][mt*16 + l15] = sP[mt];
      reds2[w][mt*16 + l15] = s2P[mt];
    }
  }
  __syncthreads();
  if (tid < 64) {
    float s = reds[0][tid] + reds[1][tid] + reds[2][tid] + reds[3][tid];
    float s2 = reds2[0][tid] + reds2[1][tid] + reds2[2][tid] + reds2[3][tid];
    float m = s * (1.f/128.f);
    float var = s2 * (1.f/128.f) - m*m;
    mv[tid][0] = m;
    mv[tid][1] = rsqrtf(var + 1e-5f);
  }
  __syncthreads();

  float4 gv[2], bv2[2];
  #pragma unroll
  for (int dt = 0; dt < 2; ++dt) {
    gv[dt]  = *(const float4*)&g1[w*32 + dt*16 + l4*4];
    bv2[dt] = *(const float4*)&b1n[w*32 + dt*16 + l4*4];
  }
  #pragma unroll
  for (int mt = 0; mt < 4; ++mt) {
    int row = mt*16 + l15;
    float m = mv[row][0], inv = mv[row][1];
    float lg[8];
    #pragma unroll
    for (int e = 0; e < 8; ++e) lg[e] = 0.f;
    #pragma unroll
    for (int dt = 0; dt < 2; ++dt) {
      int dim = w*32 + dt*16 + l4*4;
      f32x4 r = y[dt][mt];
      float o0 = (r[0]-m)*inv*((float*)&gv[dt])[0] + ((float*)&bv2[dt])[0];
      float o1 = (r[1]-m)*inv*((float*)&gv[dt])[1] + ((float*)&bv2[dt])[1];
      float o2 = (r[2]-m)*inv*((float*)&gv[dt])[2] + ((float*)&bv2[dt])[2];
      float o3 = (r[3]-m)*inv*((float*)&gv[dt])[3] + ((float*)&bv2[dt])[3];
      float4 ov; ov.x = o0; ov.y = o1; ov.z = o2; ov.w = o3;
      *(float4*)&out1[(size_t)(t0 + row) * Dd + dim] = ov;
      uint2 p; p.x = pack2bf(o0, o1); p.y = pack2bf(o2, o3);
      *(uint2*)&out1b[(size_t)(t0 + row) * Dd + dim] = p;
      #pragma unroll
      for (int e = 0; e < 8; ++e)
        lg[e] += o0*wgs[(dim+0)*8+e] + o1*wgs[(dim+1)*8+e]
               + o2*wgs[(dim+2)*8+e] + o3*wgs[(dim+3)*8+e];
    }
    #pragma unroll
    for (int e = 0; e < 8; ++e) {
      lg[e] += __shfl_xor(lg[e], 16, 64);
      lg[e] += __shfl_xor(lg[e], 32, 64);
    }
    if (l4 == 0) {
      #pragma unroll
      for (int e = 0; e < 8; ++e) atomicAdd(&lgs[row*8 + e], lg[e]);
    }
  }
  __syncthreads();

  int i0 = 0, i1 = -1, p0 = 0, p1 = 0;
  float g0 = 0.f, gg1 = 0.f;
  if (tid < 64) {
    float lgv[8];
    #pragma unroll
    for (int e = 0; e < 8; ++e) lgv[e] = lgs[tid*8 + e];
    float v0 = lgv[0];
    #pragma unroll
    for (int e = 1; e < 8; ++e) if (lgv[e] > v0) { v0 = lgv[e]; i0 = e; }
    float v1 = -INFINITY;
    #pragma unroll
    for (int e = 0; e < 8; ++e) if (e != i0 && lgv[e] > v1) { v1 = lgv[e]; i1 = e; }
    g0 = 1.f / (1.f + __expf(v1 - v0));
    gg1 = 1.f - g0;
    atomicAdd(&s_imp[i0], g0);  atomicAdd(&s_imp[i1], gg1);
    atomicAdd(&s_load[i0], 1.f); atomicAdd(&s_load[i1], 1.f);
    p0 = atomicAdd(&s_cnt[i0], 1);
    p1 = atomicAdd(&s_cnt[i1], 1);
  }
  __syncthreads();
  if (tid < 8) {
    s_base[tid] = atomicAdd(&cnt[tid], s_cnt[tid]);
    atomicAdd(&imp[tid], s_imp[tid]);
    atomicAdd(&loadv[tid], s_load[tid]);
  }
  __syncthreads();
  if (tid < 64) {
    int t = t0 + tid;
    int o0 = i0 * Tt + s_base[i0] + p0;
    etok[o0] = t;               egate[o0] = g0;
    int o1 = i1 * Tt + s_base[i1] + p1;
    etok[o1] = t | (1 << 30);   egate[o1] = gg1;
  }
}

// ---------------- K6: grouped sparse MoE FFN (MFMA bf16, bf16 in/out) ----------------
__global__ __launch_bounds__(256) void moe_kernel(const short* __restrict__ out1b,
    const short* __restrict__ W1t, const float* __restrict__ b1,
    const short* __restrict__ W2t, const float* __restrict__ b2,
    const int* __restrict__ cnt, const int* __restrict__ etok, const float* __restrict__ egate,
    short* __restrict__ moe0, short* __restrict__ moe1)
{
  __shared__ short xs[64][136];
  __shared__ short hs[64][136];
  __shared__ int els[64];
  __shared__ float gls[64];

  const int e = blockIdx.y;
  const int count = cnt[e];
  const int t0 = blockIdx.x * 64;
  if (t0 >= count) return;
  const int nt = min(64, count - t0);
  const int tid = threadIdx.x;

  if (tid < 64) {
    int idx = (tid < nt) ? tid : 0;
    els[tid] = etok[e * Tt + t0 + idx];
    gls[tid] = (tid < nt) ? egate[e * Tt + t0 + tid] : 0.f;
  }
  __syncthreads();

  #pragma unroll
  for (int it = 0; it < 8; ++it) {
    int lin = it * 256 + tid;
    int r = lin >> 5;
    int c4 = (lin & 31) << 2;
    int tok = els[r] & 0x3FFFFFFF;
    *(uint2*)&xs[r][c4] = *(const uint2*)&out1b[(size_t)tok * Dd + c4];
  }
  __syncthreads();

  const int lane = tid & 63;
  const int w = tid >> 6;
  const int l15 = lane & 15;
  const int l4 = lane >> 4;

  f32x4 zero4 = {0.f, 0.f, 0.f, 0.f};
  f32x4 y[2][4];
  #pragma unroll
  for (int dt = 0; dt < 2; ++dt)
    #pragma unroll
    for (int mt = 0; mt < 4; ++mt) y[dt][mt] = zero4;

  const short* W1p = W1t + (size_t)e * FFd * Dd;
  const short* W2p = W2t + (size_t)e * Dd * FFd;

  for (int ch = 0; ch < 4; ++ch) {
    f32x4 h[2][4];
    #pragma unroll
    for (int ft = 0; ft < 2; ++ft)
      #pragma unroll
      for (int mt = 0; mt < 4; ++mt) h[ft][mt] = zero4;

    #pragma unroll
    for (int kt = 0; kt < 4; ++kt) {
      bf16x8 a0 = *(const bf16x8*)&W1p[(size_t)(ch*128 + w*32 + 0*16 + l15) * Dd + kt*32 + l4*8];
      bf16x8 a1 = *(const bf16x8*)&W1p[(size_t)(ch*128 + w*32 + 1*16 + l15) * Dd + kt*32 + l4*8];
      bf16x8 bm[4];
      #pragma unroll
      for (int mt = 0; mt < 4; ++mt)
        bm[mt] = *(const bf16x8*)&xs[mt*16 + l15][kt*32 + l4*8];
      #pragma unroll
      for (int mt = 0; mt < 4; ++mt) {
        h[0][mt] = __builtin_amdgcn_mfma_f32_16x16x32_bf16(a0, bm[mt], h[0][mt], 0, 0, 0);
        h[1][mt] = __builtin_amdgcn_mfma_f32_16x16x32_bf16(a1, bm[mt], h[1][mt], 0, 0, 0);
      }
    }

    float4 b1v0 = *(const float4*)&b1[e*FFd + ch*128 + w*32 + 0*16 + l4*4];
    float4 b1v1 = *(const float4*)&b1[e*FFd + ch*128 + w*32 + 1*16 + l4*4];
    __syncthreads();
    #pragma unroll
    for (int mt = 0; mt < 4; ++mt) {
      uint2 p0, p1;
      p0.x = pack2bf(fmaxf(h[0][mt][0] + b1v0.x, 0.f), fmaxf(h[0][mt][1] + b1v0.y, 0.f));
      p0.y = pack2bf(fmaxf(h[0][mt][2] + b1v0.z, 0.f), fmaxf(h[0][mt][3] + b1v0.w, 0.f));
      *(uint2*)&hs[mt*16 + l15][w*32 + 0*16 + l4*4] = p0;
      p1.x = pack2bf(fmaxf(h[1][mt][0] + b1v1.x, 0.f), fmaxf(h[1][mt][1] + b1v1.y, 0.f));
      p1.y = pack2bf(fmaxf(h[1][mt][2] + b1v1.z, 0.f), fmaxf(h[1][mt][3] + b1v1.w, 0.f));
      *(uint2*)&hs[mt*16 + l15][w*32 + 1*16 + l4*4] = p1;
    }
    __syncthreads();

    #pragma unroll
    for (int kt = 0; kt < 4; ++kt) {
      bf16x8 a0 = *(const bf16x8*)&W2p[(size_t)(w*32 + 0*16 + l15) * FFd + ch*128 + kt*32 + l4*8];
      bf16x8 a1 = *(const bf16x8*)&W2p[(size_t)(w*32 + 1*16 + l15) * FFd + ch*128 + kt*32 + l4*8];
      bf16x8 bm[4];
      #pragma unroll
      for (int mt = 0; mt < 4; ++mt)
        bm[mt] = *(const bf16x8*)&hs[mt*16 + l15][kt*32 + l4*8];
      #pragma unroll
      for (int mt = 0; mt < 4; ++mt) {
        y[0][mt] = __builtin_amdgcn_mfma_f32_16x16x32_bf16(a0, bm[mt], y[0][mt], 0, 0, 0);
        y[1][mt] = __builtin_amdgcn_mfma_f32_16x16x32_bf16(a1, bm[mt], y[1][mt], 0, 0, 0);
      }
    }
  }

  float4 b2v[2];
  b2v[0] = *(const float4*)&b2[e*Dd + w*32 + 0*16 + l4*4];
  b2v[1] = *(const float4*)&b2[e*Dd + w*32 + 1*16 + l4*4];
  #pragma unroll
  for (int mt = 0; mt < 4; ++mt) {
    int m = mt*16 + l15;
    if (m < nt) {
      int raw = els[m];
      int t = raw & 0x3FFFFFFF;
      float g = gls[m];
      short* basep = (raw & (1 << 30)) ? moe1 : moe0;
      #pragma unroll
      for (int dt = 0; dt < 2; ++dt) {
        float v0 = g * (y[dt][mt][0] + ((dt == 0) ? b2v[0].x : b2v[1].x));
        float v1 = g * (y[dt][mt][1] + ((dt == 0) ? b2v[0].y : b2v[1].y));
        float v2 = g * (y[dt][mt][2] + ((dt == 0) ? b2v[0].z : b2v[1].z));
        float v3 = g * (y[dt][mt][3] + ((dt == 0) ? b2v[0].w : b2v[1].w));
        uint2 p; p.x = pack2bf(v0, v1); p.y = pack2bf(v2, v3);
        *(uint2*)&basep[(size_t)t * Dd + w*32 + dt*16 + l4*4] = p;
      }
    }
  }
}

// ---------------- K7: residual + LN2 -> d_out (+ loss in block 0) ----------------
// grid 3200, block 256 (one wave per token; no LDS).
__global__ __launch_bounds__(256) void ln2_kernel(const float* __restrict__ out1,
    const short* __restrict__ moe0, const short* __restrict__ moe1,
    const float* __restrict__ g, const float* __restrict__ bb,
    const float* __restrict__ imp, const float* __restrict__ loadv,
    float* __restrict__ out, float* __restrict__ out_loss)
{
  const int tid = threadIdx.x;
  const int lane = tid & 63;
  const int t = blockIdx.x * 4 + (tid >> 6);
  const int j = lane * 2;

  float2 xv = *(const float2*)&out1[(size_t)t * Dd + j];
  unsigned m0 = *(const unsigned*)&moe0[(size_t)t * Dd + j];
  unsigned m1 = *(const unsigned*)&moe1[(size_t)t * Dd + j];
  union { unsigned u; float f; } a, b, c, d;
  a.u = m0 << 16; b.u = m0 & 0xFFFF0000u;
  c.u = m1 << 16; d.u = m1 & 0xFFFF0000u;
  float r0 = xv.x + a.f + c.f;
  float r1 = xv.y + b.f + d.f;

  float s = r0 + r1;
  float s2 = r0*r0 + r1*r1;
  #pragma unroll
  for (int off = 32; off > 0; off >>= 1) {
    s  += __shfl_xor(s, off, 64);
    s2 += __shfl_xor(s2, off, 64);
  }
  float mean = s * (1.f/128.f);
  float var = s2 * (1.f/128.f) - mean*mean;
  float inv = rsqrtf(var + 1e-5f);
  float2 ov;
  ov.x = (r0 - mean) * inv * g[j]   + bb[j];
  ov.y = (r1 - mean) * inv * g[j+1] + bb[j+1];
  *(float2*)&out[(size_t)t * Dd + j] = ov;

  if (blockIdx.x == 0 && tid == 0) {
    float m1s = 0.f;
    for (int e = 0; e < 8; ++e) m1s += imp[e];
    m1s *= 0.125f;
    float v1 = 0.f;
    for (int e = 0; e < 8; ++e) { float dd = imp[e] - m1s; v1 += dd * dd; }
    v1 *= 0.125f;
    float c1 = v1 / (m1s * m1s + 1e-10f);
    float m2 = 0.f;
    for (int e = 0; e < 8; ++e) m2 += loadv[e];
    m2 *= 0.125f;
    float v2 = 0.f;
    for (int e = 0; e < 8; ++e) { float dd = loadv[e] - m2; v2 += dd * dd; }
    v2 *= 0.125f;
    float c2 = v2 / (m2 * m2 + 1e-10f);
    out_loss[0] = (c1 + c2) * 0.01f;
  }
}

extern "C" void kernel_launch(void* const* d_in, const int* in_sizes, int n_in,
                              void* d_out, int out_size, void* d_ws, size_t ws_size,
                              hipStream_t stream)
{
  (void)in_sizes; (void)n_in; (void)out_size; (void)ws_size;
  const float* x      = (const float*)d_in[0];
  const float* Wq     = (const float*)d_in[1];
  const float* Wk     = (const float*)d_in[2];
  const float* Wv     = (const float*)d_in[3];
  const float* Wo     = (const float*)d_in[4];
  const float* bo     = (const float*)d_in[5];
  const float* ln1_g  = (const float*)d_in[6];
  const float* ln1_b  = (const float*)d_in[7];
  const float* w_gate = (const float*)d_in[8];
  const float* W1     = (const float*)d_in[9];
  const float* b1     = (const float*)d_in[10];
  const float* W2     = (const float*)d_in[11];
  const float* b2     = (const float*)d_in[12];
  const float* ln2_g  = (const float*)d_in[13];
  const float* ln2_b  = (const float*)d_in[14];

  // ws_size is 256 MiB — no aliasing needed, every buffer gets its own region.
  char* wsb = (char*)d_ws;
  size_t off = 0;
  float* attn    = (float*)(wsb + off); off += (size_t)Tt*Dd*4;          //  6,553,600
  float* out1    = (float*)(wsb + off); off += (size_t)Tt*Dd*4;          //  6,553,600
  short* out1b   = (short*)(wsb + off); off += (size_t)Tt*Dd*2;          //  3,276,800
  short* moe0    = (short*)(wsb + off); off += (size_t)Tt*Dd*2;          //  3,276,800
  short* moe1    = (short*)(wsb + off); off += (size_t)Tt*Dd*2;          //  3,276,800
  short* q_bf    = (short*)(wsb + off); off += (size_t)Tt*QKd*2;         //    409,600 x8 heads = [BH][400][16]
  off += (size_t)Tt*QKd*2*7;                                             //  (full 3,276,800 for q)
  short* k_bf    = (short*)(wsb + off); off += (size_t)Tt*Hh*QKd*2;      //  3,276,800
  short* v_bf    = (short*)(wsb + off); off += (size_t)Tt*Hh*QKd*2;      //  3,276,800
  short* W1t     = (short*)(wsb + off); off += (size_t)Ee*FFd*Dd*2;      //  1,048,576
  short* W2t     = (short*)(wsb + off); off += (size_t)Ee*FFd*Dd*2;      //  1,048,576
  short* wo_t    = (short*)(wsb + off); off += (size_t)Dd*Dd*2;          //     32,768
  short* qkvw    = (short*)(wsb + off); off += (size_t)384*Dd*2;         //     98,304
  int*   gmeta   = (int*)(wsb + off);   off += 256;
  int*   etok    = (int*)(wsb + off);   off += (size_t)Ee*Tt*4;          //    409,600
  float* egate   = (float*)(wsb + off); off += (size_t)Ee*Tt*4;          //    409,600

  int*   cnt   = gmeta;
  float* imp   = (float*)(gmeta + 8);
  float* loadv = (float*)(gmeta + 16);

  float* out3 = (float*)d_out;
  float* loss = out3 + Tt * Dd;

  prep_kernel<<<1088, 256, 0, stream>>>(W1, W2, Wo, Wq, Wk, Wv, W1t, W2t, wo_t, qkvw, gmeta);
  qkv_kernel<<<200, 256, 0, stream>>>(x, qkvw, q_bf, k_bf, v_bf);
  attn_kernel<<<256, 512, 0, stream>>>(q_bf, k_bf, v_bf, attn);
  proj_ln1_gate_kernel<<<200, 256, 0, stream>>>(x, attn, wo_t, bo, ln1_g, ln1_b, w_gate,
                                                out1, out1b, cnt, imp, loadv, etok, egate);
  moe_kernel<<<dim3(200, 8), 256, 0, stream>>>(out1b, W1t, b1, W2t, b2, cnt, etok, egate, moe0, moe1);
  ln2_kernel<<<3200, 256, 0, stream>>>(out1, moe0, moe1, ln2_g, ln2_b, imp, loadv, out3, loss);
}